// Round 1
// baseline (395.825 us; speedup 1.0000x reference)
//
#include <hip/hip_runtime.h>
#include <stdint.h>

typedef unsigned short u16;
typedef unsigned int   u32;

#define NB   2
#define NS   2048
#define NDIM 1024
#define NH   16
#define NDH  64
#define NBH  (NB*NH)      // 32
#define NM   (NB*NS)      // 4096
#define ATT_SCALE 0.125f

typedef __bf16 bf16x8 __attribute__((ext_vector_type(8)));
typedef float  f32x4  __attribute__((ext_vector_type(4)));

#define MFMA_BF16(a,b,c) __builtin_amdgcn_mfma_f32_16x16x32_bf16((a),(b),(c),0,0,0)

// ---------------- ws layout (bytes, all 256-aligned) ----------------
#define XBF_OFF   (256)                          // 8 MB x in bf16; later reused for attention output
#define WD_OFF    (XBF_OFF  + 8*1024*1024)       // 8 MB dense quaternion weights (q,k,v,o)
#define BIAS_OFF  (WD_OFF   + 8*1024*1024)       // 16 KB fp32 biases
#define QB_OFF    (BIAS_OFF + 16384)             // 8 MB Q (b,h,s,dh) bf16
#define KB_OFF    (QB_OFF   + 8*1024*1024)       // 8 MB K
#define VB_OFF    (KB_OFF   + 8*1024*1024)       // 8 MB V
// total ~48.25 MB

__device__ __forceinline__ float bf2f(u16 h){
  union { u32 u; float f; } v; v.u = ((u32)h) << 16; return v.f;
}
__device__ __forceinline__ u16 f2bf(float f){
  union { float f; u32 u; } v; v.f = f;
  u32 r = (v.u >> 16) & 1u;
  return (u16)((v.u + 0x7fffu + r) >> 16);
}
__device__ __forceinline__ float load_val(const void* p, int i, int isbf){
  return isbf ? bf2f(((const u16*)p)[i]) : ((const float*)p)[i];
}
// async global->LDS, 16B per lane (lds dest: wave-uniform base + lane*16)
__device__ __forceinline__ void gl_lds16(const u16* g, u16* l){
  __builtin_amdgcn_global_load_lds(
      (__attribute__((address_space(1))) void*)(uintptr_t)g,
      (__attribute__((address_space(3))) void*)(uintptr_t)l,
      16, 0, 0);
}

// ---------------- dtype detector ----------------
// bf16 buffer: ~all 16-bit halves have sane exponents. fp32 buffer: low halves
// are mantissa bits -> ~24% sane. Threshold in between.
__global__ void detect_kernel(const u16* __restrict__ x, int* __restrict__ flag){
  __shared__ int cnt;
  if (threadIdx.x == 0) cnt = 0;
  __syncthreads();
  int ok = 0;
  int base = threadIdx.x * 16;
  for (int i = base; i < base + 16; ++i){
    u16 h = x[i];
    int e = (h >> 7) & 0xFF;
    if ((e > 96 && e < 158) || ((h & 0x7FFF) == 0)) ok++;
  }
  atomicAdd(&cnt, ok);
  __syncthreads();
  if (threadIdx.x == 0) *flag = (cnt > 3600) ? 1 : 0;
}

// ---------------- x -> bf16 ----------------
__global__ void conv_x_kernel(const void* __restrict__ xin, u16* __restrict__ xbf,
                              const int* __restrict__ flag){
  int isbf = *flag;
  int t = blockIdx.x * 256 + threadIdx.x;       // 524288 threads, 8 elems each
  if (isbf){
    ((uint4*)xbf)[t] = ((const uint4*)xin)[t];
  } else {
    const float4* f4 = (const float4*)xin;
    float4 a = f4[2*t], b = f4[2*t+1];
    ushort4 lo = { f2bf(a.x), f2bf(a.y), f2bf(a.z), f2bf(a.w) };
    ushort4 hi = { f2bf(b.x), f2bf(b.y), f2bf(b.z), f2bf(b.w) };
    ((ushort4*)xbf)[2*t]   = lo;
    ((ushort4*)xbf)[2*t+1] = hi;
  }
}

// ---------------- dense quaternion weight build ----------------
struct QPtrs { const void* w[16]; const void* b[4]; };

__global__ void build_w_kernel(QPtrs ptrs, u16* __restrict__ wd,
                               float* __restrict__ biasf, const int* __restrict__ flag){
  int isbf = *flag;
  int idx = blockIdx.x * 256 + threadIdx.x;     // 1M threads
  int n = idx & 255, m = (idx >> 8) & 255, c = (idx >> 16) & 3, p = idx >> 18;
  int src = m * 256 + n;
  float vr = load_val(ptrs.w[p*4+0], src, isbf);
  float vi = load_val(ptrs.w[p*4+1], src, isbf);
  float vj = load_val(ptrs.w[p*4+2], src, isbf);
  float vk = load_val(ptrs.w[p*4+3], src, isbf);
  float o0, o1, o2, o3;
  switch (c){
    case 0:  o0 = vr; o1 = -vi; o2 = -vj; o3 = -vk; break;  // o_r row
    case 1:  o0 = vi; o1 =  vr; o2 = -vj; o3 =  vk; break;  // o_i row
    case 2:  o0 = vj; o1 =  vi; o2 =  vr; o3 = -vk; break;  // o_j row
    default: o0 = vk; o1 = -vi; o2 =  vj; o3 =  vr; break;  // o_k row
  }
  ushort4 sv = { f2bf(o0), f2bf(o1), f2bf(o2), f2bf(o3) };
  *(ushort4*)&wd[(size_t)p * 1048576 + (size_t)(4*m + c) * 1024 + 4*n] = sv;
  if (idx < 4096){
    int pp = idx >> 10, oo = idx & 1023;
    biasf[idx] = load_val(ptrs.b[pp], oo, isbf);
  }
}

// ---------------- GEMM: C[M,N] = A[M,K] * W[N,K]^T + bias ----------------
// MODE 0: A=Xbf M=4096, W=Wd(q|k|v) N=3072 -> scatter to Q/K/V (b,h,s,dh) bf16
// MODE 1: A=attn-out M=4096, W=Wd(o) N=1024 -> d_out (+dtype flag)
template <int MODE>
__global__ __launch_bounds__(256)
void gemm_kernel(const u16* __restrict__ A, const u16* __restrict__ Bw,
                 const float* __restrict__ bias,
                 u16* __restrict__ qb, u16* __restrict__ kb, u16* __restrict__ vb,
                 void* __restrict__ dout, const int* __restrict__ flag){
  __shared__ u16 sA[128 * 32];
  __shared__ u16 sB[128 * 32];
  int tid = threadIdx.x, w = tid >> 6, lane = tid & 63, quad = lane >> 4, l16 = lane & 15;
  int n0 = blockIdx.x * 128, m0 = blockIdx.y * 128;

  f32x4 acc[4][4];
#pragma unroll
  for (int i = 0; i < 4; ++i)
#pragma unroll
    for (int j = 0; j < 4; ++j) acc[i][j] = (f32x4){0.f, 0.f, 0.f, 0.f};

  int eo = w * 512 + lane * 8;                // element offset in 128x32 tile
  int r0 = eo >> 5, c0 = eo & 31;
  const u16* ga = A  + (size_t)(m0 + r0) * 1024 + c0;
  const u16* gb = Bw + (size_t)(n0 + r0) * 1024 + c0;
  u16* la = &sA[eo];
  u16* lb = &sB[eo];
  int mw = (w & 1) * 64, nw = (w >> 1) * 64;

  for (int k0 = 0; k0 < 1024; k0 += 32){
#pragma unroll
    for (int i = 0; i < 2; ++i){
      gl_lds16(ga + (size_t)i * 65536 + k0, la + i * 2048);
      gl_lds16(gb + (size_t)i * 65536 + k0, lb + i * 2048);
    }
    __syncthreads();
    bf16x8 af[4], bfr[4];
#pragma unroll
    for (int mt = 0; mt < 4; ++mt)
      af[mt] = *(const bf16x8*)&sA[(mw + mt*16 + l16) * 32 + quad * 8];
#pragma unroll
    for (int nt = 0; nt < 4; ++nt)
      bfr[nt] = *(const bf16x8*)&sB[(nw + nt*16 + l16) * 32 + quad * 8];
#pragma unroll
    for (int mt = 0; mt < 4; ++mt)
#pragma unroll
      for (int nt = 0; nt < 4; ++nt)
        acc[mt][nt] = MFMA_BF16(af[mt], bfr[nt], acc[mt][nt]);
    __syncthreads();
  }

  if (MODE == 0){
    u16* bufs[3] = { qb, kb, vb };
#pragma unroll
    for (int mt = 0; mt < 4; ++mt){
      int row = m0 + mw + mt*16 + quad*4;     // + r  (stays within one b: 4-aligned)
      int b = row >> 11;
#pragma unroll
      for (int nt = 0; nt < 4; ++nt){
        int col = n0 + nw + nt*16 + l16;
        int proj = col >> 10, o = col & 1023;
        int h = o >> 6, d = o & 63;
        float bv = bias[col];
        u16* dst = bufs[proj];
#pragma unroll
        for (int r = 0; r < 4; ++r){
          int seq = (row + r) & 2047;
          dst[((size_t)((b*16 + h) * 2048 + seq)) * 64 + d] = f2bf(acc[mt][nt][r] + bv);
        }
      }
    }
  } else {
    int isbf = *flag;
#pragma unroll
    for (int mt = 0; mt < 4; ++mt){
      int row = m0 + mw + mt*16 + quad*4;
#pragma unroll
      for (int nt = 0; nt < 4; ++nt){
        int col = n0 + nw + nt*16 + l16;
        float bv = bias[col];
#pragma unroll
        for (int r = 0; r < 4; ++r){
          float val = acc[mt][nt][r] + bv;
          size_t addr = (size_t)(row + r) * 1024 + col;
          if (isbf) ((u16*)dout)[addr] = f2bf(val);
          else      ((float*)dout)[addr] = val;
        }
      }
    }
  }
}

// ---------------- RoPE (in-place, (b,h,s,dh) bf16) ----------------
__global__ void rope_kernel(u16* __restrict__ buf){
  int idx = blockIdx.x * 256 + threadIdx.x;   // 1M threads: (bh, s, g)
  int g = idx & 15, s = (idx >> 4) & 2047, bh = idx >> 15;
  size_t base = ((size_t)bh * 2048 + s) * 64 + g * 4;
  ushort4 xv = *(ushort4*)&buf[base];
  float xr = bf2f(xv.x), xi = bf2f(xv.y), xj = bf2f(xv.z), xk = bf2f(xv.w);
  // inv = 10000^(-g/16);  ln(10000)/16 = 0.57564627324851148...
  float inv = __expf(-(float)g * 0.5756462732485115f);
  float ang = (float)s * inv;
  float co = cosf(ang), si = sinf(ang);
  int ax = g % 3;
  float ui = (ax == 0) ? si : 0.f;
  float uj = (ax == 1) ? si : 0.f;
  float uk = (ax == 2) ? si : 0.f;
  float pr = co*xr - ui*xi - uj*xj - uk*xk;
  float pi = co*xi + ui*xr + uj*xk - uk*xj;
  float pj = co*xj - ui*xk + uj*xr + uk*xi;
  float pk = co*xk + ui*xj - uj*xi + uk*xr;
  ushort4 res = { f2bf(pr), f2bf(pi), f2bf(pj), f2bf(pk) };
  *(ushort4*)&buf[base] = res;
}

// ---------------- flash attention (causal), 64-row Q tile / block ----------------
__global__ __launch_bounds__(256)
void attn_kernel(const u16* __restrict__ Q, const u16* __restrict__ K,
                 const u16* __restrict__ V, u16* __restrict__ Ob){
  __shared__ u16 sQ[64*64], sK[64*64], sV[64*64], sP[4*16*64];
  int qt = blockIdx.x, bh = blockIdx.y;
  int tid = threadIdx.x, w = tid >> 6, lane = tid & 63, quad = lane >> 4, l16 = lane & 15;
  size_t base = (size_t)bh * NS * NDH;

  const uint4* gq = (const uint4*)(Q + base + (size_t)qt * 4096);
  ((uint4*)sQ)[tid]       = gq[tid];
  ((uint4*)sQ)[tid + 256] = gq[tid + 256];

  f32x4 oacc[4];
#pragma unroll
  for (int i = 0; i < 4; ++i) oacc[i] = (f32x4){0.f, 0.f, 0.f, 0.f};
  float m_i[4] = {-1e30f, -1e30f, -1e30f, -1e30f};
  float l_i[4] = {0.f, 0.f, 0.f, 0.f};
  int qrow = qt*64 + w*16 + quad*4;           // + r
  u16* sp = &sP[w * 1024];
  const __bf16* svb = (const __bf16*)sV;

  for (int kt = 0; kt <= qt; ++kt){
    __syncthreads();
    const uint4* gk = (const uint4*)(K + base + (size_t)kt * 4096);
    const uint4* gv = (const uint4*)(V + base + (size_t)kt * 4096);
    ((uint4*)sK)[tid]       = gk[tid];
    ((uint4*)sK)[tid + 256] = gk[tid + 256];
    ((uint4*)sV)[tid]       = gv[tid];
    ((uint4*)sV)[tid + 256] = gv[tid + 256];
    __syncthreads();

    // S = Q K^T  (wave rows w*16..+15, cols kt*64..+63)
    f32x4 sacc[4];
#pragma unroll
    for (int nt = 0; nt < 4; ++nt) sacc[nt] = (f32x4){0.f, 0.f, 0.f, 0.f};
#pragma unroll
    for (int kc = 0; kc < 2; ++kc){
      bf16x8 af = *(const bf16x8*)&sQ[(w*16 + l16)*64 + kc*32 + quad*8];
#pragma unroll
      for (int nt = 0; nt < 4; ++nt){
        bf16x8 bk = *(const bf16x8*)&sK[(nt*16 + l16)*64 + kc*32 + quad*8];
        sacc[nt] = MFMA_BF16(af, bk, sacc[nt]);
      }
    }
    // scale + causal mask (only diagonal tile needs masking)
    if (kt == qt){
#pragma unroll
      for (int nt = 0; nt < 4; ++nt){
        int col = kt*64 + nt*16 + l16;
#pragma unroll
        for (int r = 0; r < 4; ++r){
          float sv = sacc[nt][r] * ATT_SCALE;
          sacc[nt][r] = (col > qrow + r) ? -1e30f : sv;
        }
      }
    } else {
#pragma unroll
      for (int nt = 0; nt < 4; ++nt)
#pragma unroll
        for (int r = 0; r < 4; ++r) sacc[nt][r] *= ATT_SCALE;
    }
    // online softmax per row (rows live in 16-lane groups; xor 1/2/4/8 reduces)
#pragma unroll
    for (int r = 0; r < 4; ++r){
      float mx = fmaxf(fmaxf(sacc[0][r], sacc[1][r]), fmaxf(sacc[2][r], sacc[3][r]));
      mx = fmaxf(mx, __shfl_xor(mx, 1));
      mx = fmaxf(mx, __shfl_xor(mx, 2));
      mx = fmaxf(mx, __shfl_xor(mx, 4));
      mx = fmaxf(mx, __shfl_xor(mx, 8));
      float mnew = fmaxf(m_i[r], mx);
      float alpha = __expf(m_i[r] - mnew);
      m_i[r] = mnew;
      float rs = 0.f;
#pragma unroll
      for (int nt = 0; nt < 4; ++nt){
        float p = __expf(sacc[nt][r] - mnew);
        sacc[nt][r] = p;
        rs += p;
      }
      rs += __shfl_xor(rs, 1);
      rs += __shfl_xor(rs, 2);
      rs += __shfl_xor(rs, 4);
      rs += __shfl_xor(rs, 8);
      l_i[r] = l_i[r] * alpha + rs;
#pragma unroll
      for (int nt = 0; nt < 4; ++nt) oacc[nt][r] *= alpha;
      // P: C-layout -> LDS (wave-private 16x64)
#pragma unroll
      for (int nt = 0; nt < 4; ++nt)
        sp[(quad*4 + r)*64 + nt*16 + l16] = f2bf(sacc[nt][r]);
    }
    __syncthreads();   // ordering insurance for LDS P round-trip
    // O += P * V
#pragma unroll
    for (int kc = 0; kc < 2; ++kc){
      bf16x8 pf = *(const bf16x8*)&sp[l16*64 + kc*32 + quad*8];
#pragma unroll
      for (int nt = 0; nt < 4; ++nt){
        bf16x8 vf;
#pragma unroll
        for (int j = 0; j < 8; ++j)
          vf[j] = svb[(kc*32 + quad*8 + j)*64 + nt*16 + l16];
        oacc[nt] = MFMA_BF16(pf, vf, oacc[nt]);
      }
    }
  }
  // write (b, s, h*64+d) bf16
  int b = bh >> 4, h = bh & 15;
#pragma unroll
  for (int nt = 0; nt < 4; ++nt)
#pragma unroll
    for (int r = 0; r < 4; ++r){
      int seq = qrow + r;
      Ob[((size_t)(b*2048 + seq)) * 1024 + h*64 + nt*16 + l16] = f2bf(oacc[nt][r] / l_i[r]);
    }
}

// ---------------- launcher ----------------
extern "C" void kernel_launch(void* const* d_in, const int* in_sizes, int n_in,
                              void* d_out, int out_size, void* d_ws, size_t ws_size,
                              hipStream_t stream){
  (void)in_sizes; (void)n_in; (void)out_size; (void)ws_size;
  char* ws = (char*)d_ws;
  int*   flag  = (int*)ws;
  u16*   Xbf   = (u16*)(ws + XBF_OFF);
  u16*   Wd    = (u16*)(ws + WD_OFF);
  float* biasf = (float*)(ws + BIAS_OFF);
  u16*   Qb    = (u16*)(ws + QB_OFF);
  u16*   Kb    = (u16*)(ws + KB_OFF);
  u16*   Vb    = (u16*)(ws + VB_OFF);
  u16*   Ab    = Xbf;   // reuse x-bf16 region for attention output

  detect_kernel<<<1, 256, 0, stream>>>((const u16*)d_in[0], flag);
  conv_x_kernel<<<2048, 256, 0, stream>>>(d_in[0], Xbf, flag);

  QPtrs ptrs;
  for (int p = 0; p < 4; ++p){
    for (int wi = 0; wi < 4; ++wi) ptrs.w[p*4 + wi] = d_in[2 + p*5 + wi];
    ptrs.b[p] = d_in[2 + p*5 + 4];
  }
  build_w_kernel<<<4096, 256, 0, stream>>>(ptrs, Wd, biasf, flag);

  gemm_kernel<0><<<dim3(24, 32), 256, 0, stream>>>(Xbf, Wd, biasf, Qb, Kb, Vb, nullptr, flag);
  rope_kernel<<<4096, 256, 0, stream>>>(Qb);
  rope_kernel<<<4096, 256, 0, stream>>>(Kb);
  attn_kernel<<<dim3(32, 32), 256, 0, stream>>>(Qb, Kb, Vb, Ab);
  gemm_kernel<1><<<dim3(8, 32), 256, 0, stream>>>(Ab, Wd + 3*1048576, biasf + 3072,
                                                  nullptr, nullptr, nullptr, d_out, flag);
}

// Round 2
// 296.940 us; speedup vs baseline: 1.3330x; 1.3330x over previous
//
#include <hip/hip_runtime.h>
#include <stdint.h>

typedef unsigned short u16;
typedef unsigned int   u32;

#define NB   2
#define NS   2048
#define NDIM 1024
#define NH   16
#define NDH  64
// SCALE * log2(e) = 0.125 * 1.4426950408889634
#define QSCALE 0.18033688011112042f

typedef __bf16 bf16x8 __attribute__((ext_vector_type(8)));
typedef float  f32x4  __attribute__((ext_vector_type(4)));

#define MFMA_BF16(a,b,c) __builtin_amdgcn_mfma_f32_16x16x32_bf16((a),(b),(c),0,0,0)

// ---------------- ws layout (bytes) ----------------
#define XBF_OFF   (256)                          // 8 MB x bf16; reused as attention output
#define WD_OFF    (XBF_OFF  + 8*1024*1024)       // 8 MB dense quaternion weights (q,k,v,o)
#define BIAS_OFF  (WD_OFF   + 8*1024*1024)       // 16 KB fp32 biases
#define QB_OFF    (BIAS_OFF + 16384)             // 8 MB Q (b,h,s,dh) bf16 (pre-scaled by QSCALE in rope)
#define KB_OFF    (QB_OFF   + 8*1024*1024)       // 8 MB K
#define VB_OFF    (KB_OFF   + 8*1024*1024)       // 8 MB V
// total ~48.25 MB

__device__ __forceinline__ float bf2f(u16 h){
  union { u32 u; float f; } v; v.u = ((u32)h) << 16; return v.f;
}
__device__ __forceinline__ u16 f2bf(float f){
  union { float f; u32 u; } v; v.f = f;
  u32 r = (v.u >> 16) & 1u;
  return (u16)((v.u + 0x7fffu + r) >> 16);
}
__device__ __forceinline__ float load_val(const void* p, int i, int isbf){
  return isbf ? bf2f(((const u16*)p)[i]) : ((const float*)p)[i];
}
__device__ __forceinline__ void gl_lds16(const u16* g, u16* l){
  __builtin_amdgcn_global_load_lds(
      (__attribute__((address_space(1))) void*)(uintptr_t)g,
      (__attribute__((address_space(3))) void*)(uintptr_t)l,
      16, 0, 0);
}

// ---------------- dtype detector ----------------
__global__ void detect_kernel(const u16* __restrict__ x, int* __restrict__ flag){
  __shared__ int cnt;
  if (threadIdx.x == 0) cnt = 0;
  __syncthreads();
  int ok = 0;
  int base = threadIdx.x * 16;
  for (int i = base; i < base + 16; ++i){
    u16 h = x[i];
    int e = (h >> 7) & 0xFF;
    if ((e > 96 && e < 158) || ((h & 0x7FFF) == 0)) ok++;
  }
  atomicAdd(&cnt, ok);
  __syncthreads();
  if (threadIdx.x == 0) *flag = (cnt > 3600) ? 1 : 0;
}

// ---------------- x -> bf16 ----------------
__global__ void conv_x_kernel(const void* __restrict__ xin, u16* __restrict__ xbf,
                              const int* __restrict__ flag){
  int isbf = *flag;
  int t = blockIdx.x * 256 + threadIdx.x;
  if (isbf){
    ((uint4*)xbf)[t] = ((const uint4*)xin)[t];
  } else {
    const float4* f4 = (const float4*)xin;
    float4 a = f4[2*t], b = f4[2*t+1];
    ushort4 lo = { f2bf(a.x), f2bf(a.y), f2bf(a.z), f2bf(a.w) };
    ushort4 hi = { f2bf(b.x), f2bf(b.y), f2bf(b.z), f2bf(b.w) };
    ((ushort4*)xbf)[2*t]   = lo;
    ((ushort4*)xbf)[2*t+1] = hi;
  }
}

// ---------------- dense quaternion weight build ----------------
struct QPtrs { const void* w[16]; const void* b[4]; };

__global__ void build_w_kernel(QPtrs ptrs, u16* __restrict__ wd,
                               float* __restrict__ biasf, const int* __restrict__ flag){
  int isbf = *flag;
  int idx = blockIdx.x * 256 + threadIdx.x;
  int n = idx & 255, m = (idx >> 8) & 255, c = (idx >> 16) & 3, p = idx >> 18;
  int src = m * 256 + n;
  float vr = load_val(ptrs.w[p*4+0], src, isbf);
  float vi = load_val(ptrs.w[p*4+1], src, isbf);
  float vj = load_val(ptrs.w[p*4+2], src, isbf);
  float vk = load_val(ptrs.w[p*4+3], src, isbf);
  float o0, o1, o2, o3;
  switch (c){
    case 0:  o0 = vr; o1 = -vi; o2 = -vj; o3 = -vk; break;
    case 1:  o0 = vi; o1 =  vr; o2 = -vj; o3 =  vk; break;
    case 2:  o0 = vj; o1 =  vi; o2 =  vr; o3 = -vk; break;
    default: o0 = vk; o1 = -vi; o2 =  vj; o3 =  vr; break;
  }
  ushort4 sv = { f2bf(o0), f2bf(o1), f2bf(o2), f2bf(o3) };
  *(ushort4*)&wd[(size_t)p * 1048576 + (size_t)(4*m + c) * 1024 + 4*n] = sv;
  if (idx < 4096){
    int pp = idx >> 10, oo = idx & 1023;
    biasf[idx] = load_val(ptrs.b[pp], oo, isbf);
  }
}

// ---------------- GEMM mode0: X*Wqkv^T -> scatter Q/K/V (b,h,s,dh) ----------------
__global__ __launch_bounds__(256)
void gemm_qkv_kernel(const u16* __restrict__ A, const u16* __restrict__ Bw,
                     const float* __restrict__ bias,
                     u16* __restrict__ qb, u16* __restrict__ kb, u16* __restrict__ vb){
  __shared__ u16 sA[128 * 32];
  __shared__ u16 sB[128 * 32];
  int tid = threadIdx.x, w = tid >> 6, lane = tid & 63, quad = lane >> 4, l16 = lane & 15;
  int n0 = blockIdx.x * 128, m0 = blockIdx.y * 128;

  f32x4 acc[4][4];
#pragma unroll
  for (int i = 0; i < 4; ++i)
#pragma unroll
    for (int j = 0; j < 4; ++j) acc[i][j] = (f32x4){0.f, 0.f, 0.f, 0.f};

  int eo = w * 512 + lane * 8;
  int r0 = eo >> 5, c0 = eo & 31;
  const u16* ga = A  + (size_t)(m0 + r0) * 1024 + c0;
  const u16* gb = Bw + (size_t)(n0 + r0) * 1024 + c0;
  u16* la = &sA[eo];
  u16* lb = &sB[eo];
  int mw = (w & 1) * 64, nw = (w >> 1) * 64;

  for (int k0 = 0; k0 < 1024; k0 += 32){
#pragma unroll
    for (int i = 0; i < 2; ++i){
      gl_lds16(ga + (size_t)i * 65536 + k0, la + i * 2048);
      gl_lds16(gb + (size_t)i * 65536 + k0, lb + i * 2048);
    }
    __syncthreads();
    bf16x8 af[4], bfr[4];
#pragma unroll
    for (int mt = 0; mt < 4; ++mt)
      af[mt] = *(const bf16x8*)&sA[(mw + mt*16 + l16) * 32 + quad * 8];
#pragma unroll
    for (int nt = 0; nt < 4; ++nt)
      bfr[nt] = *(const bf16x8*)&sB[(nw + nt*16 + l16) * 32 + quad * 8];
#pragma unroll
    for (int mt = 0; mt < 4; ++mt)
#pragma unroll
      for (int nt = 0; nt < 4; ++nt)
        acc[mt][nt] = MFMA_BF16(af[mt], bfr[nt], acc[mt][nt]);
    __syncthreads();
  }

  u16* bufs[3] = { qb, kb, vb };
#pragma unroll
  for (int mt = 0; mt < 4; ++mt){
    int row = m0 + mw + mt*16 + quad*4;
    int b = row >> 11;
#pragma unroll
    for (int nt = 0; nt < 4; ++nt){
      int col = n0 + nw + nt*16 + l16;
      int proj = col >> 10, o = col & 1023;
      int h = o >> 6, d = o & 63;
      float bv = bias[col];
      u16* dst = bufs[proj];
#pragma unroll
      for (int r = 0; r < 4; ++r){
        int seq = (row + r) & 2047;
        dst[((size_t)((b*16 + h) * 2048 + seq)) * 64 + d] = f2bf(acc[mt][nt][r] + bv);
      }
    }
  }
}

// ---------------- GEMM mode1: 64x128 tile, attn-out * Wo^T -> d_out ----------------
__global__ __launch_bounds__(256)
void gemm_o_kernel(const u16* __restrict__ A, const u16* __restrict__ Bw,
                   const float* __restrict__ bias, void* __restrict__ dout,
                   const int* __restrict__ flag){
  __shared__ u16 sA[64 * 32];
  __shared__ u16 sB[128 * 32];
  int tid = threadIdx.x, w = tid >> 6, lane = tid & 63, quad = lane >> 4, l16 = lane & 15;
  int n0 = blockIdx.x * 128, m0 = blockIdx.y * 64;

  f32x4 acc[2][4];
#pragma unroll
  for (int i = 0; i < 2; ++i)
#pragma unroll
    for (int j = 0; j < 4; ++j) acc[i][j] = (f32x4){0.f, 0.f, 0.f, 0.f};

  int mw = (w & 1) * 32, nw = (w >> 1) * 64;

  for (int k0 = 0; k0 < 1024; k0 += 32){
#pragma unroll
    for (int i = 0; i < 3; ++i){
      int c = w * 3 + i;                  // 12 chunks of 512 elements: 4 sA + 8 sB
      int eo = (c < 4 ? c : c - 4) * 512 + lane * 8;
      int r0 = eo >> 5, c0 = eo & 31;
      if (c < 4) gl_lds16(A  + (size_t)(m0 + r0) * 1024 + k0 + c0, &sA[eo]);
      else       gl_lds16(Bw + (size_t)(n0 + r0) * 1024 + k0 + c0, &sB[eo]);
    }
    __syncthreads();
    bf16x8 af[2], bfr[4];
#pragma unroll
    for (int mt = 0; mt < 2; ++mt)
      af[mt] = *(const bf16x8*)&sA[(mw + mt*16 + l16) * 32 + quad * 8];
#pragma unroll
    for (int nt = 0; nt < 4; ++nt)
      bfr[nt] = *(const bf16x8*)&sB[(nw + nt*16 + l16) * 32 + quad * 8];
#pragma unroll
    for (int mt = 0; mt < 2; ++mt)
#pragma unroll
      for (int nt = 0; nt < 4; ++nt)
        acc[mt][nt] = MFMA_BF16(af[mt], bfr[nt], acc[mt][nt]);
    __syncthreads();
  }

  int isbf = *flag;
#pragma unroll
  for (int mt = 0; mt < 2; ++mt){
    int row = m0 + mw + mt*16 + quad*4;
#pragma unroll
    for (int nt = 0; nt < 4; ++nt){
      int col = n0 + nw + nt*16 + l16;
      float bv = bias[col];
#pragma unroll
      for (int r = 0; r < 4; ++r){
        float val = acc[mt][nt][r] + bv;
        size_t addr = (size_t)(row + r) * 1024 + col;
        if (isbf) ((u16*)dout)[addr] = f2bf(val);
        else      ((float*)dout)[addr] = val;
      }
    }
  }
}

// ---------------- RoPE: Q (pre-scaled by QSCALE) and K in one kernel ----------------
__global__ void rope_kernel(u16* __restrict__ qb, u16* __restrict__ kb){
  int idx = blockIdx.x * 256 + threadIdx.x;   // 2M threads: (which, bh, s, g)
  int which = idx >> 20;
  int r = idx & 1048575;
  u16* buf = which ? kb : qb;
  int g = r & 15, s = (r >> 4) & 2047, bh = r >> 15;
  size_t base = ((size_t)bh * 2048 + s) * 64 + g * 4;
  ushort4 xv = *(ushort4*)&buf[base];
  float xr = bf2f(xv.x), xi = bf2f(xv.y), xj = bf2f(xv.z), xk = bf2f(xv.w);
  float inv = __expf(-(float)g * 0.5756462732485115f);   // 10000^(-g/16)
  float ang = (float)s * inv;
  float co = cosf(ang), si = sinf(ang);
  float sc = which ? 1.0f : QSCALE;
  co *= sc; si *= sc;
  int ax = g % 3;
  float ui = (ax == 0) ? si : 0.f;
  float uj = (ax == 1) ? si : 0.f;
  float uk = (ax == 2) ? si : 0.f;
  float pr = co*xr - ui*xi - uj*xj - uk*xk;
  float pi = co*xi + ui*xr + uj*xk - uk*xj;
  float pj = co*xj - ui*xk + uj*xr + uk*xi;
  float pk = co*xk + ui*xj - uj*xi + uk*xr;
  ushort4 res = { f2bf(pr), f2bf(pi), f2bf(pj), f2bf(pk) };
  *(ushort4*)&buf[base] = res;
}

// ---------------- flash attention, BQ=128, fixed-max exp2 softmax ----------------
// Q pre-scaled by SCALE*log2e. sK/sV padded stride 72; sV stored transposed
// (d-major) with 8-element xor swizzle on the seq column to spread banks.
#define PSTR 72
__device__ __forceinline__ int swz(int d, int c){ return c ^ (((d >> 3) & 7) << 3); }

__global__ __launch_bounds__(256, 3)
void attn_kernel(const u16* __restrict__ Q, const u16* __restrict__ K,
                 const u16* __restrict__ V, u16* __restrict__ Ob){
  __shared__ u16 sK[64 * PSTR];
  __shared__ u16 sV[64 * PSTR];          // sV[d][swz(d,seq)]
  __shared__ u16 sP[8 * 16 * PSTR];      // per (wave,group) 16x64 P tile
  int qt = 15 - (int)blockIdx.x;         // longest blocks first
  int bh = blockIdx.y;
  int tid = threadIdx.x, w = tid >> 6, lane = tid & 63, quad = lane >> 4, l16 = lane & 15;
  size_t base = (size_t)bh * NS * NDH;
  int rowbase = qt * 128 + w * 32;

  // Q fragments in registers (per wave: rows rowbase+g*16+l16, k = kc*32+quad*8)
  bf16x8 qf[2][2];
#pragma unroll
  for (int g = 0; g < 2; ++g)
#pragma unroll
    for (int kc = 0; kc < 2; ++kc)
      qf[g][kc] = *(const bf16x8*)(Q + base + (size_t)(rowbase + g*16 + l16) * 64 + kc*32 + quad*8);

  f32x4 oacc[2][4];
  float lsum[2][4];
#pragma unroll
  for (int g = 0; g < 2; ++g)
#pragma unroll
    for (int i = 0; i < 4; ++i){ oacc[g][i] = (f32x4){0.f,0.f,0.f,0.f}; lsum[g][i] = 0.f; }

  int srow = tid >> 3;            // 0..31
  int sch  = (tid & 7) * 8;       // 0..56
  int ktmax = 2*qt + 1;

  for (int kt = 0; kt <= ktmax; ++kt){
    int kcol = kt * 64;
    __syncthreads();
#pragma unroll
    for (int p = 0; p < 2; ++p){
      int row = p*32 + srow;
      *(uint4*)&sK[row * PSTR + sch] = *(const uint4*)(K + base + (size_t)(kcol + row) * 64 + sch);
      union { uint4 v; u16 s[8]; } vv;
      vv.v = *(const uint4*)(V + base + (size_t)(kcol + row) * 64 + sch);
#pragma unroll
      for (int j = 0; j < 8; ++j){
        int d = sch + j;
        sV[d * PSTR + swz(d, row)] = vv.s[j];
      }
    }
    __syncthreads();

    if (kcol <= rowbase + 31){
      // K and V^T fragments, shared across both row groups
      bf16x8 bk[2][4], vf[2][4];
#pragma unroll
      for (int kc = 0; kc < 2; ++kc)
#pragma unroll
        for (int nt = 0; nt < 4; ++nt){
          int dn = nt*16 + l16;
          bk[kc][nt] = *(const bf16x8*)&sK[dn * PSTR + kc*32 + quad*8];
          vf[kc][nt] = *(const bf16x8*)&sV[dn * PSTR + swz(dn, kc*32 + quad*8)];
        }
#pragma unroll
      for (int g = 0; g < 2; ++g){
        int G0 = rowbase + g*16;
        if (kcol <= G0 + 15){
          f32x4 sacc[4];
#pragma unroll
          for (int nt = 0; nt < 4; ++nt) sacc[nt] = (f32x4){0.f,0.f,0.f,0.f};
#pragma unroll
          for (int kc = 0; kc < 2; ++kc)
#pragma unroll
            for (int nt = 0; nt < 4; ++nt)
              sacc[nt] = MFMA_BF16(qf[g][kc], bk[kc][nt], sacc[nt]);

          __bf16* sp = (__bf16*)&sP[(w*2 + g) * 16 * PSTR];
          if (kcol + 63 > G0){          // diagonal tile: per-element causal mask
#pragma unroll
            for (int nt = 0; nt < 4; ++nt){
              int col = kcol + nt*16 + l16;
#pragma unroll
              for (int r = 0; r < 4; ++r){
                int row = G0 + quad*4 + r;
                float pp = (col <= row) ? __builtin_amdgcn_exp2f(sacc[nt][r]) : 0.f;
                lsum[g][r] += pp;
                sp[(quad*4 + r) * PSTR + nt*16 + l16] = (__bf16)pp;
              }
            }
          } else {
#pragma unroll
            for (int nt = 0; nt < 4; ++nt)
#pragma unroll
              for (int r = 0; r < 4; ++r){
                float pp = __builtin_amdgcn_exp2f(sacc[nt][r]);
                lsum[g][r] += pp;
                sp[(quad*4 + r) * PSTR + nt*16 + l16] = (__bf16)pp;
              }
          }
          // O += P * V  (wave-private LDS roundtrip; no barrier needed)
#pragma unroll
          for (int kc = 0; kc < 2; ++kc){
            bf16x8 pf = *(const bf16x8*)&sp[l16 * PSTR + kc*32 + quad*8];
#pragma unroll
            for (int nt = 0; nt < 4; ++nt)
              oacc[g][nt] = MFMA_BF16(pf, vf[kc][nt], oacc[g][nt]);
          }
        }
      }
    }
  }

  // final 16-lane l reduction + normalize + write (b, s, h*64+d)
  int b = bh >> 4, h = bh & 15;
#pragma unroll
  for (int g = 0; g < 2; ++g)
#pragma unroll
    for (int r = 0; r < 4; ++r){
      float l = lsum[g][r];
      l += __shfl_xor(l, 1); l += __shfl_xor(l, 2);
      l += __shfl_xor(l, 4); l += __shfl_xor(l, 8);
      float invl = 1.f / l;
      int seq = rowbase + g*16 + quad*4 + r;
#pragma unroll
      for (int nt = 0; nt < 4; ++nt)
        Ob[((size_t)(b*2048 + seq)) * 1024 + h*64 + nt*16 + l16] = f2bf(oacc[g][nt][r] * invl);
    }
}

// ---------------- launcher ----------------
extern "C" void kernel_launch(void* const* d_in, const int* in_sizes, int n_in,
                              void* d_out, int out_size, void* d_ws, size_t ws_size,
                              hipStream_t stream){
  (void)in_sizes; (void)n_in; (void)out_size; (void)ws_size;
  char* ws = (char*)d_ws;
  int*   flag  = (int*)ws;
  u16*   Xbf   = (u16*)(ws + XBF_OFF);
  u16*   Wd    = (u16*)(ws + WD_OFF);
  float* biasf = (float*)(ws + BIAS_OFF);
  u16*   Qb    = (u16*)(ws + QB_OFF);
  u16*   Kb    = (u16*)(ws + KB_OFF);
  u16*   Vb    = (u16*)(ws + VB_OFF);
  u16*   Ab    = Xbf;   // reuse x-bf16 region for attention output

  detect_kernel<<<1, 256, 0, stream>>>((const u16*)d_in[0], flag);
  conv_x_kernel<<<2048, 256, 0, stream>>>(d_in[0], Xbf, flag);

  QPtrs ptrs;
  for (int p = 0; p < 4; ++p){
    for (int wi = 0; wi < 4; ++wi) ptrs.w[p*4 + wi] = d_in[2 + p*5 + wi];
    ptrs.b[p] = d_in[2 + p*5 + 4];
  }
  build_w_kernel<<<4096, 256, 0, stream>>>(ptrs, Wd, biasf, flag);

  gemm_qkv_kernel<<<dim3(24, 32), 256, 0, stream>>>(Xbf, Wd, biasf, Qb, Kb, Vb);
  rope_kernel<<<8192, 256, 0, stream>>>(Qb, Kb);
  attn_kernel<<<dim3(16, 32), 256, 0, stream>>>(Qb, Kb, Vb, Ab);
  gemm_o_kernel<<<dim3(8, 64), 256, 0, stream>>>(Ab, Wd + 3*1048576, biasf + 3072,
                                                 d_out, flag);
}

// Round 3
// 274.391 us; speedup vs baseline: 1.4426x; 1.0822x over previous
//
#include <hip/hip_runtime.h>
#include <stdint.h>

typedef unsigned short u16;
typedef unsigned int   u32;

#define NB   2
#define NS   2048
#define NDIM 1024
#define NH   16
#define NDH  64
// SCALE * log2(e) = 0.125 * 1.4426950408889634
#define QSCALE 0.18033688011112042f

typedef __bf16 bf16x8 __attribute__((ext_vector_type(8)));
typedef float  f32x4  __attribute__((ext_vector_type(4)));

#define MFMA_BF16(a,b,c) __builtin_amdgcn_mfma_f32_16x16x32_bf16((a),(b),(c),0,0,0)

// ---------------- ws layout (bytes) ----------------
#define XBF_OFF   (256)                          // 8 MB x bf16; reused as combined attention output
#define WD_OFF    (XBF_OFF  + 8*1024*1024)       // 8 MB dense quaternion weights (q,k,v,o)
#define BIAS_OFF  (WD_OFF   + 8*1024*1024)       // 16 KB fp32 biases
#define QB_OFF    (BIAS_OFF + 16384)             // 8 MB Q (bh,s,d) bf16 (pre-scaled by QSCALE)
#define KB_OFF    (QB_OFF   + 8*1024*1024)       // 8 MB K (bh,s,d)
#define VT_OFF    (KB_OFF   + 8*1024*1024)       // 8 MB V^T (bh,d,s)
#define OP_OFF    (VT_OFF   + 8*1024*1024)       // 16 MB O partials bf16 [split][bh][s][d]
#define LP_OFF    (OP_OFF   + 16*1024*1024)      // 512 KB l partials fp32 [split][bh][s]
// total ~57 MB

__device__ __forceinline__ float bf2f(u16 h){
  union { u32 u; float f; } v; v.u = ((u32)h) << 16; return v.f;
}
__device__ __forceinline__ u16 f2bf(float f){
  union { float f; u32 u; } v; v.f = f;
  u32 r = (v.u >> 16) & 1u;
  return (u16)((v.u + 0x7fffu + r) >> 16);
}
__device__ __forceinline__ float load_val(const void* p, int i, int isbf){
  return isbf ? bf2f(((const u16*)p)[i]) : ((const float*)p)[i];
}
__device__ __forceinline__ void gl_lds16(const u16* g, u16* l){
  __builtin_amdgcn_global_load_lds(
      (__attribute__((address_space(1))) void*)(uintptr_t)g,
      (__attribute__((address_space(3))) void*)(uintptr_t)l,
      16, 0, 0);
}

// ---------------- dtype detector ----------------
__global__ void detect_kernel(const u16* __restrict__ x, int* __restrict__ flag){
  __shared__ int cnt;
  if (threadIdx.x == 0) cnt = 0;
  __syncthreads();
  int ok = 0;
  int base = threadIdx.x * 16;
  for (int i = base; i < base + 16; ++i){
    u16 h = x[i];
    int e = (h >> 7) & 0xFF;
    if ((e > 96 && e < 158) || ((h & 0x7FFF) == 0)) ok++;
  }
  atomicAdd(&cnt, ok);
  __syncthreads();
  if (threadIdx.x == 0) *flag = (cnt > 3600) ? 1 : 0;
}

// ---------------- x -> bf16 ----------------
__global__ void conv_x_kernel(const void* __restrict__ xin, u16* __restrict__ xbf,
                              const int* __restrict__ flag){
  int isbf = *flag;
  int t = blockIdx.x * 256 + threadIdx.x;
  if (isbf){
    ((uint4*)xbf)[t] = ((const uint4*)xin)[t];
  } else {
    const float4* f4 = (const float4*)xin;
    float4 a = f4[2*t], b = f4[2*t+1];
    ushort4 lo = { f2bf(a.x), f2bf(a.y), f2bf(a.z), f2bf(a.w) };
    ushort4 hi = { f2bf(b.x), f2bf(b.y), f2bf(b.z), f2bf(b.w) };
    ((ushort4*)xbf)[2*t]   = lo;
    ((ushort4*)xbf)[2*t+1] = hi;
  }
}

// ---------------- dense quaternion weight build ----------------
struct QPtrs { const void* w[16]; const void* b[4]; };

__global__ void build_w_kernel(QPtrs ptrs, u16* __restrict__ wd,
                               float* __restrict__ biasf, const int* __restrict__ flag){
  int isbf = *flag;
  int idx = blockIdx.x * 256 + threadIdx.x;
  int n = idx & 255, m = (idx >> 8) & 255, c = (idx >> 16) & 3, p = idx >> 18;
  int src = m * 256 + n;
  float vr = load_val(ptrs.w[p*4+0], src, isbf);
  float vi = load_val(ptrs.w[p*4+1], src, isbf);
  float vj = load_val(ptrs.w[p*4+2], src, isbf);
  float vk = load_val(ptrs.w[p*4+3], src, isbf);
  float o0, o1, o2, o3;
  switch (c){
    case 0:  o0 = vr; o1 = -vi; o2 = -vj; o3 = -vk; break;
    case 1:  o0 = vi; o1 =  vr; o2 = -vj; o3 =  vk; break;
    case 2:  o0 = vj; o1 =  vi; o2 =  vr; o3 = -vk; break;
    default: o0 = vk; o1 = -vi; o2 =  vj; o3 =  vr; break;
  }
  ushort4 sv = { f2bf(o0), f2bf(o1), f2bf(o2), f2bf(o3) };
  *(ushort4*)&wd[(size_t)p * 1048576 + (size_t)(4*m + c) * 1024 + 4*n] = sv;
  if (idx < 4096){
    int pp = idx >> 10, oo = idx & 1023;
    biasf[idx] = load_val(ptrs.b[pp], oo, isbf);
  }
}

// ---------------- GEMM: X*Wqkv^T -> Q/K (bh,s,d) and V^T (bh,d,s) ----------------
__global__ __launch_bounds__(256)
void gemm_qkv_kernel(const u16* __restrict__ A, const u16* __restrict__ Bw,
                     const float* __restrict__ bias,
                     u16* __restrict__ qb, u16* __restrict__ kb, u16* __restrict__ vt){
  __shared__ u16 sA[128 * 32];
  __shared__ u16 sB[128 * 32];
  int tid = threadIdx.x, w = tid >> 6, lane = tid & 63, quad = lane >> 4, l16 = lane & 15;
  int n0 = blockIdx.x * 128, m0 = blockIdx.y * 128;

  f32x4 acc[4][4];
#pragma unroll
  for (int i = 0; i < 4; ++i)
#pragma unroll
    for (int j = 0; j < 4; ++j) acc[i][j] = (f32x4){0.f, 0.f, 0.f, 0.f};

  int eo = w * 512 + lane * 8;
  int r0 = eo >> 5, c0 = eo & 31;
  const u16* ga = A  + (size_t)(m0 + r0) * 1024 + c0;
  const u16* gb = Bw + (size_t)(n0 + r0) * 1024 + c0;
  u16* la = &sA[eo];
  u16* lb = &sB[eo];
  int mw = (w & 1) * 64, nw = (w >> 1) * 64;

  for (int k0 = 0; k0 < 1024; k0 += 32){
#pragma unroll
    for (int i = 0; i < 2; ++i){
      gl_lds16(ga + (size_t)i * 65536 + k0, la + i * 2048);
      gl_lds16(gb + (size_t)i * 65536 + k0, lb + i * 2048);
    }
    __syncthreads();
    bf16x8 af[4], bfr[4];
#pragma unroll
    for (int mt = 0; mt < 4; ++mt)
      af[mt] = *(const bf16x8*)&sA[(mw + mt*16 + l16) * 32 + quad * 8];
#pragma unroll
    for (int nt = 0; nt < 4; ++nt)
      bfr[nt] = *(const bf16x8*)&sB[(nw + nt*16 + l16) * 32 + quad * 8];
#pragma unroll
    for (int mt = 0; mt < 4; ++mt)
#pragma unroll
      for (int nt = 0; nt < 4; ++nt)
        acc[mt][nt] = MFMA_BF16(af[mt], bfr[nt], acc[mt][nt]);
    __syncthreads();
  }

#pragma unroll
  for (int mt = 0; mt < 4; ++mt){
    int row = m0 + mw + mt*16 + quad*4;
    int b = row >> 11, seq0 = row & 2047;
#pragma unroll
    for (int nt = 0; nt < 4; ++nt){
      int col = n0 + nw + nt*16 + l16;
      int proj = col >> 10, o = col & 1023;
      int h = o >> 6, d = o & 63;
      float bv = bias[col];
      if (proj == 2){
        // V^T: [bh][d][s], 4 consecutive seq -> one 8B store
        ushort4 pv = { f2bf(acc[mt][nt][0] + bv), f2bf(acc[mt][nt][1] + bv),
                       f2bf(acc[mt][nt][2] + bv), f2bf(acc[mt][nt][3] + bv) };
        *(ushort4*)&vt[((size_t)((b*16 + h) * 64 + d)) * 2048 + seq0] = pv;
      } else {
        u16* dst = proj ? kb : qb;
#pragma unroll
        for (int r = 0; r < 4; ++r)
          dst[((size_t)((b*16 + h) * 2048 + seq0 + r)) * 64 + d] = f2bf(acc[mt][nt][r] + bv);
      }
    }
  }
}

// ---------------- GEMM: attn-out * Wo^T -> d_out ----------------
__global__ __launch_bounds__(256)
void gemm_o_kernel(const u16* __restrict__ A, const u16* __restrict__ Bw,
                   const float* __restrict__ bias, void* __restrict__ dout,
                   const int* __restrict__ flag){
  __shared__ u16 sA[64 * 32];
  __shared__ u16 sB[128 * 32];
  int tid = threadIdx.x, w = tid >> 6, lane = tid & 63, quad = lane >> 4, l16 = lane & 15;
  int n0 = blockIdx.x * 128, m0 = blockIdx.y * 64;

  f32x4 acc[2][4];
#pragma unroll
  for (int i = 0; i < 2; ++i)
#pragma unroll
    for (int j = 0; j < 4; ++j) acc[i][j] = (f32x4){0.f, 0.f, 0.f, 0.f};

  int mw = (w & 1) * 32, nw = (w >> 1) * 64;

  for (int k0 = 0; k0 < 1024; k0 += 32){
#pragma unroll
    for (int i = 0; i < 3; ++i){
      int c = w * 3 + i;
      int eo = (c < 4 ? c : c - 4) * 512 + lane * 8;
      int r0 = eo >> 5, c0 = eo & 31;
      if (c < 4) gl_lds16(A  + (size_t)(m0 + r0) * 1024 + k0 + c0, &sA[eo]);
      else       gl_lds16(Bw + (size_t)(n0 + r0) * 1024 + k0 + c0, &sB[eo]);
    }
    __syncthreads();
    bf16x8 af[2], bfr[4];
#pragma unroll
    for (int mt = 0; mt < 2; ++mt)
      af[mt] = *(const bf16x8*)&sA[(mw + mt*16 + l16) * 32 + quad * 8];
#pragma unroll
    for (int nt = 0; nt < 4; ++nt)
      bfr[nt] = *(const bf16x8*)&sB[(nw + nt*16 + l16) * 32 + quad * 8];
#pragma unroll
    for (int mt = 0; mt < 2; ++mt)
#pragma unroll
      for (int nt = 0; nt < 4; ++nt)
        acc[mt][nt] = MFMA_BF16(af[mt], bfr[nt], acc[mt][nt]);
    __syncthreads();
  }

  int isbf = *flag;
#pragma unroll
  for (int mt = 0; mt < 2; ++mt){
    int row = m0 + mw + mt*16 + quad*4;
#pragma unroll
    for (int nt = 0; nt < 4; ++nt){
      int col = n0 + nw + nt*16 + l16;
      float bv = bias[col];
#pragma unroll
      for (int r = 0; r < 4; ++r){
        float val = acc[mt][nt][r] + bv;
        size_t addr = (size_t)(row + r) * 1024 + col;
        if (isbf) ((u16*)dout)[addr] = f2bf(val);
        else      ((float*)dout)[addr] = val;
      }
    }
  }
}

// ---------------- RoPE: Q (pre-scaled) and K, fast trig ----------------
__global__ void rope_kernel(u16* __restrict__ qb, u16* __restrict__ kb){
  int idx = blockIdx.x * 256 + threadIdx.x;   // 2M threads: (which, bh, s, g)
  int which = idx >> 20;
  int r = idx & 1048575;
  u16* buf = which ? kb : qb;
  int g = r & 15, s = (r >> 4) & 2047, bh = r >> 15;
  size_t base = ((size_t)bh * 2048 + s) * 64 + g * 4;
  ushort4 xv = *(ushort4*)&buf[base];
  float xr = bf2f(xv.x), xi = bf2f(xv.y), xj = bf2f(xv.z), xk = bf2f(xv.w);
  // inv = 10000^(-g/16) = exp2(-g * log2(10000)/16)
  float inv = __builtin_amdgcn_exp2f(-(float)g * 0.8304820237218405f);
  float ang = (float)s * inv;
  float co = __cosf(ang), si = __sinf(ang);
  float sc = which ? 1.0f : QSCALE;
  co *= sc; si *= sc;
  int ax = g % 3;
  float ui = (ax == 0) ? si : 0.f;
  float uj = (ax == 1) ? si : 0.f;
  float uk = (ax == 2) ? si : 0.f;
  float pr = co*xr - ui*xi - uj*xj - uk*xk;
  float pi = co*xi + ui*xr + uj*xk - uk*xj;
  float pj = co*xj - ui*xk + uj*xr + uk*xi;
  float pk = co*xk + ui*xj - uj*xi + uk*xr;
  ushort4 res = { f2bf(pr), f2bf(pi), f2bf(pj), f2bf(pk) };
  *(ushort4*)&buf[base] = res;
}

// ---------------- flash attention: BQ=128, kt-split x2, async dbuf staging ----------------
// Fixed-max exp2 softmax -> partials are additive across splits.
// K (bh,s,d) and V^T (bh,d,s) staged via global_load_lds with XOR chunk swizzle
// applied on the GLOBAL address side (LDS dest is lane-contiguous by HW).
#define PSTR 72

__global__ __launch_bounds__(256, 3)
void attn_kernel(const u16* __restrict__ Q, const u16* __restrict__ K,
                 const u16* __restrict__ Vt, u16* __restrict__ OP,
                 float* __restrict__ LP){
  __shared__ u16 sK[2][4096];
  __shared__ u16 sV[2][4096];
  __shared__ u16 sP[4][16 * PSTR];
  int qt  = 15 - (int)blockIdx.x;           // longest first
  int spl = blockIdx.y;                     // kt-split 0/1
  int bh  = blockIdx.z;
  int tid = threadIdx.x, w = tid >> 6, lane = tid & 63, quad = lane >> 4, l16 = lane & 15;
  size_t kbase = (size_t)bh * 2048 * 64;    // K: [s][d]
  size_t vbase = (size_t)bh * 64 * 2048;    // Vt: [d][s]
  int rowbase = qt * 128 + w * 32;

  // Q fragments in registers
  bf16x8 qf[2][2];
#pragma unroll
  for (int g = 0; g < 2; ++g)
#pragma unroll
    for (int kc = 0; kc < 2; ++kc)
      qf[g][kc] = *(const bf16x8*)(Q + kbase + (size_t)(rowbase + g*16 + l16) * 64 + kc*32 + quad*8);

  f32x4 oacc[2][4];
  float lsum[2][4];
#pragma unroll
  for (int g = 0; g < 2; ++g)
#pragma unroll
    for (int i = 0; i < 4; ++i){ oacc[g][i] = (f32x4){0.f,0.f,0.f,0.f}; lsum[g][i] = 0.f; }

  int kt0 = spl ? (qt + 1) : 0;
  int ntiles = qt + 1;

  // stage tile kt into buffer b: 4 x global_load_lds (2 K + 2 V), swizzled
  // chunk slot = w*128 + p*64 + lane; row = slot>>3, c = slot&7, dc = c ^ (row&7)
  auto stage = [&](int kt, int b){
    int kcol = kt * 64;
#pragma unroll
    for (int p = 0; p < 2; ++p){
      int slot = w*128 + p*64 + lane;
      int row = slot >> 3, dc = (slot & 7) ^ (row & 7);
      gl_lds16(K  + kbase + (size_t)(kcol + row) * 64 + dc*8, &sK[b][(w*128 + p*64) * 8]);
      gl_lds16(Vt + vbase + (size_t)row * 2048 + kcol + dc*8, &sV[b][(w*128 + p*64) * 8]);
    }
  };

  stage(kt0, 0);
  for (int i = 0; i < ntiles; ++i){
    int kcol = (kt0 + i) * 64;
    __syncthreads();                         // drains stage(i); prior buf reads done
    if (i + 1 < ntiles) stage(kt0 + i + 1, (i + 1) & 1);
    const u16* bK = sK[i & 1];
    const u16* bV = sV[i & 1];

    if (kcol <= rowbase + 31){
      bf16x8 bk[2][4], vf[2][4];
#pragma unroll
      for (int kc = 0; kc < 2; ++kc)
#pragma unroll
        for (int nt = 0; nt < 4; ++nt){
          int rw = nt*16 + l16;
          int ch = ((kc*4 + quad) ^ (rw & 7)) * 8;
          bk[kc][nt] = *(const bf16x8*)&bK[rw*64 + ch];
          vf[kc][nt] = *(const bf16x8*)&bV[rw*64 + ch];
        }
#pragma unroll
      for (int g = 0; g < 2; ++g){
        int G0 = rowbase + g*16;
        if (kcol <= G0 + 15){
          f32x4 sacc[4];
#pragma unroll
          for (int nt = 0; nt < 4; ++nt) sacc[nt] = (f32x4){0.f,0.f,0.f,0.f};
#pragma unroll
          for (int kc = 0; kc < 2; ++kc)
#pragma unroll
            for (int nt = 0; nt < 4; ++nt)
              sacc[nt] = MFMA_BF16(qf[g][kc], bk[kc][nt], sacc[nt]);

          __bf16* sp = (__bf16*)&sP[w][0];
          if (kcol + 63 > G0){               // diagonal band: per-element mask
#pragma unroll
            for (int nt = 0; nt < 4; ++nt){
              int col = kcol + nt*16 + l16;
#pragma unroll
              for (int r = 0; r < 4; ++r){
                int row = G0 + quad*4 + r;
                float pp = (col <= row) ? __builtin_amdgcn_exp2f(sacc[nt][r]) : 0.f;
                lsum[g][r] += pp;
                sp[(quad*4 + r) * PSTR + nt*16 + l16] = (__bf16)pp;
              }
            }
          } else {
#pragma unroll
            for (int nt = 0; nt < 4; ++nt)
#pragma unroll
              for (int r = 0; r < 4; ++r){
                float pp = __builtin_amdgcn_exp2f(sacc[nt][r]);
                lsum[g][r] += pp;
                sp[(quad*4 + r) * PSTR + nt*16 + l16] = (__bf16)pp;
              }
          }
          // O += P * V (wave-private LDS roundtrip, no barrier)
#pragma unroll
          for (int kc = 0; kc < 2; ++kc){
            bf16x8 pf = *(const bf16x8*)&sp[l16 * PSTR + kc*32 + quad*8];
#pragma unroll
            for (int nt = 0; nt < 4; ++nt)
              oacc[g][nt] = MFMA_BF16(pf, vf[kc][nt], oacc[g][nt]);
          }
        }
      }
    }
  }

  // write partials (unconditional: zero partials for inactive groups)
  size_t obase = ((size_t)(spl*32 + bh)) * 2048;
#pragma unroll
  for (int g = 0; g < 2; ++g)
#pragma unroll
    for (int r = 0; r < 4; ++r){
      float l = lsum[g][r];
      l += __shfl_xor(l, 1); l += __shfl_xor(l, 2);
      l += __shfl_xor(l, 4); l += __shfl_xor(l, 8);
      int row = rowbase + g*16 + quad*4 + r;
      if (l16 == 0) LP[obase + row] = l;
#pragma unroll
      for (int nt = 0; nt < 4; ++nt)
        OP[(obase + row) * 64 + nt*16 + l16] = f2bf(oacc[g][nt][r]);
    }
}

// ---------------- combine splits -> Ab (b, s, h*64+d) bf16 ----------------
__global__ void combine_kernel(const u16* __restrict__ OP, const float* __restrict__ LP,
                               u16* __restrict__ Ab){
  int idx = blockIdx.x * 256 + threadIdx.x;  // 512K threads: (bh, s, dc)
  int dc = idx & 7, s = (idx >> 3) & 2047, bh = idx >> 14;
  size_t r0 = (size_t)bh * 2048 + s, r1 = (size_t)(32 + bh) * 2048 + s;
  float invl = 1.f / (LP[r0] + LP[r1]);
  union { uint4 v; u16 h[8]; } a0, a1; ushort4 o[2];
  a0.v = *(const uint4*)&OP[r0 * 64 + dc*8];
  a1.v = *(const uint4*)&OP[r1 * 64 + dc*8];
#pragma unroll
  for (int p = 0; p < 2; ++p)
#pragma unroll
    for (int j = 0; j < 4; ++j)
      ((u16*)&o[p])[j] = f2bf((bf2f(a0.h[p*4+j]) + bf2f(a1.h[p*4+j])) * invl);
  int b = bh >> 4, h = bh & 15;
  u16* dst = &Ab[((size_t)(b*2048 + s)) * 1024 + h*64 + dc*8];
  *(ushort4*)dst = o[0];
  *(ushort4*)(dst + 4) = o[1];
}

// ---------------- launcher ----------------
extern "C" void kernel_launch(void* const* d_in, const int* in_sizes, int n_in,
                              void* d_out, int out_size, void* d_ws, size_t ws_size,
                              hipStream_t stream){
  (void)in_sizes; (void)n_in; (void)out_size; (void)ws_size;
  char* ws = (char*)d_ws;
  int*   flag  = (int*)ws;
  u16*   Xbf   = (u16*)(ws + XBF_OFF);
  u16*   Wd    = (u16*)(ws + WD_OFF);
  float* biasf = (float*)(ws + BIAS_OFF);
  u16*   Qb    = (u16*)(ws + QB_OFF);
  u16*   Kb    = (u16*)(ws + KB_OFF);
  u16*   Vt    = (u16*)(ws + VT_OFF);
  u16*   OP    = (u16*)(ws + OP_OFF);
  float* LP    = (float*)(ws + LP_OFF);
  u16*   Ab    = Xbf;   // reuse x-bf16 region for combined attention output

  detect_kernel<<<1, 256, 0, stream>>>((const u16*)d_in[0], flag);
  conv_x_kernel<<<2048, 256, 0, stream>>>(d_in[0], Xbf, flag);

  QPtrs ptrs;
  for (int p = 0; p < 4; ++p){
    for (int wi = 0; wi < 4; ++wi) ptrs.w[p*4 + wi] = d_in[2 + p*5 + wi];
    ptrs.b[p] = d_in[2 + p*5 + 4];
  }
  build_w_kernel<<<4096, 256, 0, stream>>>(ptrs, Wd, biasf, flag);

  gemm_qkv_kernel<<<dim3(24, 32), 256, 0, stream>>>(Xbf, Wd, biasf, Qb, Kb, Vt);
  rope_kernel<<<8192, 256, 0, stream>>>(Qb, Kb);
  attn_kernel<<<dim3(16, 2, 32), 256, 0, stream>>>(Qb, Kb, Vt, OP, LP);
  combine_kernel<<<2048, 256, 0, stream>>>(OP, LP, Ab);
  gemm_o_kernel<<<dim3(8, 64), 256, 0, stream>>>(Ab, Wd + 3*1048576, biasf + 3072,
                                                 d_out, flag);
}

// Round 4
// 262.011 us; speedup vs baseline: 1.5107x; 1.0473x over previous
//
#include <hip/hip_runtime.h>
#include <stdint.h>

typedef unsigned short u16;
typedef unsigned int   u32;

#define NB   2
#define NS   2048
#define NDIM 1024
#define NH   16
#define NDH  64
// SCALE * log2(e) = 0.125 * 1.4426950408889634
#define QSCALE 0.18033688011112042f

typedef __bf16 bf16x8 __attribute__((ext_vector_type(8)));
typedef float  f32x4  __attribute__((ext_vector_type(4)));

#define MFMA_BF16(a,b,c) __builtin_amdgcn_mfma_f32_16x16x32_bf16((a),(b),(c),0,0,0)

// ---------------- ws layout (bytes) ----------------
#define XBF_OFF   (256)                          // 8 MB x bf16; reused as combined attention output
#define WD_OFF    (XBF_OFF  + 8*1024*1024)       // 8 MB dense quaternion weights (q,k,v,o)
#define BIAS_OFF  (WD_OFF   + 8*1024*1024)       // 16 KB fp32 biases
#define QB_OFF    (BIAS_OFF + 16384)             // 8 MB Q (bh,s,d) bf16 (pre-scaled by QSCALE)
#define KB_OFF    (QB_OFF   + 8*1024*1024)       // 8 MB K (bh,s,d)
#define VT_OFF    (KB_OFF   + 8*1024*1024)       // 8 MB V^T (bh,d,s)
#define OP_OFF    (VT_OFF   + 8*1024*1024)       // 16 MB O partials bf16 [split][bh][s][d]
#define LP_OFF    (OP_OFF   + 16*1024*1024)      // 512 KB l partials fp32 [split][bh][s]
// total ~57 MB

__device__ __forceinline__ float bf2f(u16 h){
  union { u32 u; float f; } v; v.u = ((u32)h) << 16; return v.f;
}
__device__ __forceinline__ u16 f2bf(float f){
  union { float f; u32 u; } v; v.f = f;
  u32 r = (v.u >> 16) & 1u;
  return (u16)((v.u + 0x7fffu + r) >> 16);
}
__device__ __forceinline__ float load_val(const void* p, int i, int isbf){
  return isbf ? bf2f(((const u16*)p)[i]) : ((const float*)p)[i];
}
__device__ __forceinline__ void gl_lds16(const u16* g, u16* l){
  __builtin_amdgcn_global_load_lds(
      (__attribute__((address_space(1))) void*)(uintptr_t)g,
      (__attribute__((address_space(3))) void*)(uintptr_t)l,
      16, 0, 0);
}

// ---------------- dtype detector ----------------
__global__ void detect_kernel(const u16* __restrict__ x, int* __restrict__ flag){
  __shared__ int cnt;
  if (threadIdx.x == 0) cnt = 0;
  __syncthreads();
  int ok = 0;
  int base = threadIdx.x * 16;
  for (int i = base; i < base + 16; ++i){
    u16 h = x[i];
    int e = (h >> 7) & 0xFF;
    if ((e > 96 && e < 158) || ((h & 0x7FFF) == 0)) ok++;
  }
  atomicAdd(&cnt, ok);
  __syncthreads();
  if (threadIdx.x == 0) *flag = (cnt > 3600) ? 1 : 0;
}

// ---------------- x -> bf16 ----------------
__global__ void conv_x_kernel(const void* __restrict__ xin, u16* __restrict__ xbf,
                              const int* __restrict__ flag){
  int isbf = *flag;
  int t = blockIdx.x * 256 + threadIdx.x;
  if (isbf){
    ((uint4*)xbf)[t] = ((const uint4*)xin)[t];
  } else {
    const float4* f4 = (const float4*)xin;
    float4 a = f4[2*t], b = f4[2*t+1];
    ushort4 lo = { f2bf(a.x), f2bf(a.y), f2bf(a.z), f2bf(a.w) };
    ushort4 hi = { f2bf(b.x), f2bf(b.y), f2bf(b.z), f2bf(b.w) };
    ((ushort4*)xbf)[2*t]   = lo;
    ((ushort4*)xbf)[2*t+1] = hi;
  }
}

// ---------------- dense quaternion weight build ----------------
struct QPtrs { const void* w[16]; const void* b[4]; };

__global__ void build_w_kernel(QPtrs ptrs, u16* __restrict__ wd,
                               float* __restrict__ biasf, const int* __restrict__ flag){
  int isbf = *flag;
  int idx = blockIdx.x * 256 + threadIdx.x;
  int n = idx & 255, m = (idx >> 8) & 255, c = (idx >> 16) & 3, p = idx >> 18;
  int src = m * 256 + n;
  float vr = load_val(ptrs.w[p*4+0], src, isbf);
  float vi = load_val(ptrs.w[p*4+1], src, isbf);
  float vj = load_val(ptrs.w[p*4+2], src, isbf);
  float vk = load_val(ptrs.w[p*4+3], src, isbf);
  float o0, o1, o2, o3;
  switch (c){
    case 0:  o0 = vr; o1 = -vi; o2 = -vj; o3 = -vk; break;
    case 1:  o0 = vi; o1 =  vr; o2 = -vj; o3 =  vk; break;
    case 2:  o0 = vj; o1 =  vi; o2 =  vr; o3 = -vk; break;
    default: o0 = vk; o1 = -vi; o2 =  vj; o3 =  vr; break;
  }
  ushort4 sv = { f2bf(o0), f2bf(o1), f2bf(o2), f2bf(o3) };
  *(ushort4*)&wd[(size_t)p * 1048576 + (size_t)(4*m + c) * 1024 + 4*n] = sv;
  if (idx < 4096){
    int pp = idx >> 10, oo = idx & 1023;
    biasf[idx] = load_val(ptrs.b[pp], oo, isbf);
  }
}

// ---------------- GEMM: X*Wqkv^T -> Q/K (bh,s,d) and V^T (bh,d,s) ----------------
__global__ __launch_bounds__(256)
void gemm_qkv_kernel(const u16* __restrict__ A, const u16* __restrict__ Bw,
                     const float* __restrict__ bias,
                     u16* __restrict__ qb, u16* __restrict__ kb, u16* __restrict__ vt){
  __shared__ u16 sA[128 * 32];
  __shared__ u16 sB[128 * 32];
  int tid = threadIdx.x, w = tid >> 6, lane = tid & 63, quad = lane >> 4, l16 = lane & 15;
  int n0 = blockIdx.x * 128, m0 = blockIdx.y * 128;

  f32x4 acc[4][4];
#pragma unroll
  for (int i = 0; i < 4; ++i)
#pragma unroll
    for (int j = 0; j < 4; ++j) acc[i][j] = (f32x4){0.f, 0.f, 0.f, 0.f};

  int eo = w * 512 + lane * 8;
  int r0 = eo >> 5, c0 = eo & 31;
  const u16* ga = A  + (size_t)(m0 + r0) * 1024 + c0;
  const u16* gb = Bw + (size_t)(n0 + r0) * 1024 + c0;
  u16* la = &sA[eo];
  u16* lb = &sB[eo];
  int mw = (w & 1) * 64, nw = (w >> 1) * 64;

  for (int k0 = 0; k0 < 1024; k0 += 32){
#pragma unroll
    for (int i = 0; i < 2; ++i){
      gl_lds16(ga + (size_t)i * 65536 + k0, la + i * 2048);
      gl_lds16(gb + (size_t)i * 65536 + k0, lb + i * 2048);
    }
    __syncthreads();
    bf16x8 af[4], bfr[4];
#pragma unroll
    for (int mt = 0; mt < 4; ++mt)
      af[mt] = *(const bf16x8*)&sA[(mw + mt*16 + l16) * 32 + quad * 8];
#pragma unroll
    for (int nt = 0; nt < 4; ++nt)
      bfr[nt] = *(const bf16x8*)&sB[(nw + nt*16 + l16) * 32 + quad * 8];
#pragma unroll
    for (int mt = 0; mt < 4; ++mt)
#pragma unroll
      for (int nt = 0; nt < 4; ++nt)
        acc[mt][nt] = MFMA_BF16(af[mt], bfr[nt], acc[mt][nt]);
    __syncthreads();
  }

#pragma unroll
  for (int mt = 0; mt < 4; ++mt){
    int row = m0 + mw + mt*16 + quad*4;
    int b = row >> 11, seq0 = row & 2047;
#pragma unroll
    for (int nt = 0; nt < 4; ++nt){
      int col = n0 + nw + nt*16 + l16;
      int proj = col >> 10, o = col & 1023;
      int h = o >> 6, d = o & 63;
      float bv = bias[col];
      if (proj == 2){
        ushort4 pv = { f2bf(acc[mt][nt][0] + bv), f2bf(acc[mt][nt][1] + bv),
                       f2bf(acc[mt][nt][2] + bv), f2bf(acc[mt][nt][3] + bv) };
        *(ushort4*)&vt[((size_t)((b*16 + h) * 64 + d)) * 2048 + seq0] = pv;
      } else {
        u16* dst = proj ? kb : qb;
#pragma unroll
        for (int r = 0; r < 4; ++r)
          dst[((size_t)((b*16 + h) * 2048 + seq0 + r)) * 64 + d] = f2bf(acc[mt][nt][r] + bv);
      }
    }
  }
}

// ---------------- GEMM: attn-out * Wo^T -> d_out ----------------
__global__ __launch_bounds__(256)
void gemm_o_kernel(const u16* __restrict__ A, const u16* __restrict__ Bw,
                   const float* __restrict__ bias, void* __restrict__ dout,
                   const int* __restrict__ flag){
  __shared__ u16 sA[64 * 32];
  __shared__ u16 sB[128 * 32];
  int tid = threadIdx.x, w = tid >> 6, lane = tid & 63, quad = lane >> 4, l16 = lane & 15;
  int n0 = blockIdx.x * 128, m0 = blockIdx.y * 64;

  f32x4 acc[2][4];
#pragma unroll
  for (int i = 0; i < 2; ++i)
#pragma unroll
    for (int j = 0; j < 4; ++j) acc[i][j] = (f32x4){0.f, 0.f, 0.f, 0.f};

  int mw = (w & 1) * 32, nw = (w >> 1) * 64;

  for (int k0 = 0; k0 < 1024; k0 += 32){
#pragma unroll
    for (int i = 0; i < 3; ++i){
      int c = w * 3 + i;
      int eo = (c < 4 ? c : c - 4) * 512 + lane * 8;
      int r0 = eo >> 5, c0 = eo & 31;
      if (c < 4) gl_lds16(A  + (size_t)(m0 + r0) * 1024 + k0 + c0, &sA[eo]);
      else       gl_lds16(Bw + (size_t)(n0 + r0) * 1024 + k0 + c0, &sB[eo]);
    }
    __syncthreads();
    bf16x8 af[2], bfr[4];
#pragma unroll
    for (int mt = 0; mt < 2; ++mt)
      af[mt] = *(const bf16x8*)&sA[(mw + mt*16 + l16) * 32 + quad * 8];
#pragma unroll
    for (int nt = 0; nt < 4; ++nt)
      bfr[nt] = *(const bf16x8*)&sB[(nw + nt*16 + l16) * 32 + quad * 8];
#pragma unroll
    for (int mt = 0; mt < 2; ++mt)
#pragma unroll
      for (int nt = 0; nt < 4; ++nt)
        acc[mt][nt] = MFMA_BF16(af[mt], bfr[nt], acc[mt][nt]);
    __syncthreads();
  }

  int isbf = *flag;
#pragma unroll
  for (int mt = 0; mt < 2; ++mt){
    int row = m0 + mw + mt*16 + quad*4;
#pragma unroll
    for (int nt = 0; nt < 4; ++nt){
      int col = n0 + nw + nt*16 + l16;
      float bv = bias[col];
#pragma unroll
      for (int r = 0; r < 4; ++r){
        float val = acc[mt][nt][r] + bv;
        size_t addr = (size_t)(row + r) * 1024 + col;
        if (isbf) ((u16*)dout)[addr] = f2bf(val);
        else      ((float*)dout)[addr] = val;
      }
    }
  }
}

// ---------------- RoPE: Q (pre-scaled) and K, fast trig ----------------
__global__ void rope_kernel(u16* __restrict__ qb, u16* __restrict__ kb){
  int idx = blockIdx.x * 256 + threadIdx.x;
  int which = idx >> 20;
  int r = idx & 1048575;
  u16* buf = which ? kb : qb;
  int g = r & 15, s = (r >> 4) & 2047, bh = r >> 15;
  size_t base = ((size_t)bh * 2048 + s) * 64 + g * 4;
  ushort4 xv = *(ushort4*)&buf[base];
  float xr = bf2f(xv.x), xi = bf2f(xv.y), xj = bf2f(xv.z), xk = bf2f(xv.w);
  float inv = __builtin_amdgcn_exp2f(-(float)g * 0.8304820237218405f);
  float ang = (float)s * inv;
  float co = __cosf(ang), si = __sinf(ang);
  float sc = which ? 1.0f : QSCALE;
  co *= sc; si *= sc;
  int ax = g % 3;
  float ui = (ax == 0) ? si : 0.f;
  float uj = (ax == 1) ? si : 0.f;
  float uk = (ax == 2) ? si : 0.f;
  float pr = co*xr - ui*xi - uj*xj - uk*xk;
  float pi = co*xi + ui*xr + uj*xk - uk*xj;
  float pj = co*xj - ui*xk + uj*xr + uk*xi;
  float pk = co*xk + ui*xj - uj*xi + uk*xr;
  ushort4 res = { f2bf(pr), f2bf(pi), f2bf(pj), f2bf(pk) };
  *(ushort4*)&buf[base] = res;
}

// ---------------- flash attention v4 ----------------
// O^T = V^T(P^T) formulation: only K is LDS-staged (barrier); V A-frags and Q
// are per-wave direct global loads. P relayout C->B via transposed wave-private
// LDS tile (b64 writes). kt-split x2 additive partials; LPT dispatch order.
#define SPT 20

__global__ __launch_bounds__(256, 3)
void attn_kernel(const u16* __restrict__ Q, const u16* __restrict__ K,
                 const u16* __restrict__ Vt, u16* __restrict__ OP,
                 float* __restrict__ LP){
  __shared__ u16 sK[2][4096];
  __shared__ u16 sPT[4][64 * SPT];      // per-wave P^T tile: [col 0..63][m 0..15 + pad]
  int bh  = blockIdx.x;
  int spl = blockIdx.y;
  int qt  = 15 - (int)blockIdx.z;       // LPT: longest blocks dispatched first
  int tid = threadIdx.x, w = tid >> 6, lane = tid & 63, quad = lane >> 4, l16 = lane & 15;
  size_t kbase = (size_t)bh * 2048 * 64;   // Q,K: [s][d]
  size_t vbase = (size_t)bh * 64 * 2048;   // Vt: [d][s]
  int rowbase = qt * 128 + w * 32;
  u16* spw = &sPT[w][0];

  // Q fragments in registers
  bf16x8 qf[2][2];
#pragma unroll
  for (int g = 0; g < 2; ++g)
#pragma unroll
    for (int kc = 0; kc < 2; ++kc)
      qf[g][kc] = *(const bf16x8*)(Q + kbase + (size_t)(rowbase + g*16 + l16) * 64 + kc*32 + quad*8);

  // O^T accumulators: oaccT[g][dn][r] = O[G0+l16][dn*16 + quad*4 + r]
  f32x4 oaccT[2][4];
  float lsum[2][4];
#pragma unroll
  for (int g = 0; g < 2; ++g)
#pragma unroll
    for (int i = 0; i < 4; ++i){ oaccT[g][i] = (f32x4){0.f,0.f,0.f,0.f}; lsum[g][i] = 0.f; }

  int kt0 = spl ? (qt + 1) : 0;
  int ntiles = qt + 1;

  // stage K tile kt into buffer b (XOR chunk swizzle on global side)
  auto stage = [&](int kt, int b){
    int kcol = kt * 64;
#pragma unroll
    for (int p = 0; p < 2; ++p){
      int slot = w*128 + p*64 + lane;
      int row = slot >> 3, dc = (slot & 7) ^ (row & 7);
      gl_lds16(K + kbase + (size_t)(kcol + row) * 64 + dc*8, &sK[b][(w*128 + p*64) * 8]);
    }
  };

  stage(kt0, 0);
  for (int i = 0; i < ntiles; ++i){
    int kcol = (kt0 + i) * 64;
    __syncthreads();
    if (i + 1 < ntiles) stage(kt0 + i + 1, (i + 1) & 1);
    const u16* bK = sK[i & 1];

    if (kcol <= rowbase + 31){
      // V^T A-fragments: direct global loads (shared across both groups)
      bf16x8 vf[4][2];
#pragma unroll
      for (int dn = 0; dn < 4; ++dn)
#pragma unroll
        for (int kc = 0; kc < 2; ++kc)
          vf[dn][kc] = *(const bf16x8*)(Vt + vbase + (size_t)(dn*16 + l16) * 2048
                                        + kcol + kc*32 + quad*8);
      // K B-fragments from LDS (swizzled)
      bf16x8 bk[2][4];
#pragma unroll
      for (int kc = 0; kc < 2; ++kc)
#pragma unroll
        for (int nt = 0; nt < 4; ++nt){
          int rw = nt*16 + l16;
          int ch = ((kc*4 + quad) ^ (rw & 7)) * 8;
          bk[kc][nt] = *(const bf16x8*)&bK[rw*64 + ch];
        }
#pragma unroll
      for (int g = 0; g < 2; ++g){
        int G0 = rowbase + g*16;
        if (kcol <= G0 + 15){
          f32x4 sacc[4];
#pragma unroll
          for (int nt = 0; nt < 4; ++nt) sacc[nt] = (f32x4){0.f,0.f,0.f,0.f};
#pragma unroll
          for (int kc = 0; kc < 2; ++kc)
#pragma unroll
            for (int nt = 0; nt < 4; ++nt)
              sacc[nt] = MFMA_BF16(qf[g][kc], bk[kc][nt], sacc[nt]);

          // exp2 + mask, write P^T[col][m] as packed b64 (m = quad*4 + r)
          if (kcol + 63 > G0){           // diagonal band
#pragma unroll
            for (int nt = 0; nt < 4; ++nt){
              int col = kcol + nt*16 + l16;
              ushort4 pv;
#pragma unroll
              for (int r = 0; r < 4; ++r){
                int row = G0 + quad*4 + r;
                float pp = (col <= row) ? __builtin_amdgcn_exp2f(sacc[nt][r]) : 0.f;
                lsum[g][r] += pp;
                ((u16*)&pv)[r] = f2bf(pp);
              }
              *(ushort4*)&spw[(nt*16 + l16) * SPT + quad*4] = pv;
            }
          } else {
#pragma unroll
            for (int nt = 0; nt < 4; ++nt){
              ushort4 pv;
#pragma unroll
              for (int r = 0; r < 4; ++r){
                float pp = __builtin_amdgcn_exp2f(sacc[nt][r]);
                lsum[g][r] += pp;
                ((u16*)&pv)[r] = f2bf(pp);
              }
              *(ushort4*)&spw[(nt*16 + l16) * SPT + quad*4] = pv;
            }
          }
          // O^T += Vt * P^T  (B-frag of P^T: scalar u16 LDS reads, wave-private)
#pragma unroll
          for (int kc = 0; kc < 2; ++kc){
            bf16x8 pf;
#pragma unroll
            for (int j = 0; j < 8; ++j)
              pf[j] = ((const __bf16*)spw)[(kc*32 + quad*8 + j) * SPT + l16];
#pragma unroll
            for (int dn = 0; dn < 4; ++dn)
              oaccT[g][dn] = MFMA_BF16(vf[dn][kc], pf, oaccT[g][dn]);
          }
        }
      }
    }
  }

  // redistribute row-sums: lane (quad,r) holds row quad*4+r; O^T needs row=l16
  float* scr = (float*)spw;              // wave-private scratch (P^T dead now)
#pragma unroll
  for (int g = 0; g < 2; ++g)
#pragma unroll
    for (int r = 0; r < 4; ++r){
      float l = lsum[g][r];
      l += __shfl_xor(l, 1); l += __shfl_xor(l, 2);
      l += __shfl_xor(l, 4); l += __shfl_xor(l, 8);
      if (l16 == 0) scr[g*16 + quad*4 + r] = l;
    }
  float lrow[2];
#pragma unroll
  for (int g = 0; g < 2; ++g) lrow[g] = scr[g*16 + l16];

  size_t obase = ((size_t)(spl*32 + bh)) * 2048;
#pragma unroll
  for (int g = 0; g < 2; ++g){
    int row = rowbase + g*16 + l16;
    if (quad == 0) LP[obase + row] = lrow[g];
#pragma unroll
    for (int dn = 0; dn < 4; ++dn){
      ushort4 ov = { f2bf(oaccT[g][dn][0]), f2bf(oaccT[g][dn][1]),
                     f2bf(oaccT[g][dn][2]), f2bf(oaccT[g][dn][3]) };
      *(ushort4*)&OP[(obase + row) * 64 + dn*16 + quad*4] = ov;
    }
  }
}

// ---------------- combine splits -> Ab (b, s, h*64+d) bf16 ----------------
__global__ void combine_kernel(const u16* __restrict__ OP, const float* __restrict__ LP,
                               u16* __restrict__ Ab){
  int idx = blockIdx.x * 256 + threadIdx.x;
  int dc = idx & 7, s = (idx >> 3) & 2047, bh = idx >> 14;
  size_t r0 = (size_t)bh * 2048 + s, r1 = (size_t)(32 + bh) * 2048 + s;
  float invl = 1.f / (LP[r0] + LP[r1]);
  union { uint4 v; u16 h[8]; } a0, a1; ushort4 o[2];
  a0.v = *(const uint4*)&OP[r0 * 64 + dc*8];
  a1.v = *(const uint4*)&OP[r1 * 64 + dc*8];
#pragma unroll
  for (int p = 0; p < 2; ++p)
#pragma unroll
    for (int j = 0; j < 4; ++j)
      ((u16*)&o[p])[j] = f2bf((bf2f(a0.h[p*4+j]) + bf2f(a1.h[p*4+j])) * invl);
  int b = bh >> 4, h = bh & 15;
  u16* dst = &Ab[((size_t)(b*2048 + s)) * 1024 + h*64 + dc*8];
  *(ushort4*)dst = o[0];
  *(ushort4*)(dst + 4) = o[1];
}

// ---------------- launcher ----------------
extern "C" void kernel_launch(void* const* d_in, const int* in_sizes, int n_in,
                              void* d_out, int out_size, void* d_ws, size_t ws_size,
                              hipStream_t stream){
  (void)in_sizes; (void)n_in; (void)out_size; (void)ws_size;
  char* ws = (char*)d_ws;
  int*   flag  = (int*)ws;
  u16*   Xbf   = (u16*)(ws + XBF_OFF);
  u16*   Wd    = (u16*)(ws + WD_OFF);
  float* biasf = (float*)(ws + BIAS_OFF);
  u16*   Qb    = (u16*)(ws + QB_OFF);
  u16*   Kb    = (u16*)(ws + KB_OFF);
  u16*   Vt    = (u16*)(ws + VT_OFF);
  u16*   OP    = (u16*)(ws + OP_OFF);
  float* LP    = (float*)(ws + LP_OFF);
  u16*   Ab    = Xbf;

  detect_kernel<<<1, 256, 0, stream>>>((const u16*)d_in[0], flag);
  conv_x_kernel<<<2048, 256, 0, stream>>>(d_in[0], Xbf, flag);

  QPtrs ptrs;
  for (int p = 0; p < 4; ++p){
    for (int wi = 0; wi < 4; ++wi) ptrs.w[p*4 + wi] = d_in[2 + p*5 + wi];
    ptrs.b[p] = d_in[2 + p*5 + 4];
  }
  build_w_kernel<<<4096, 256, 0, stream>>>(ptrs, Wd, biasf, flag);

  gemm_qkv_kernel<<<dim3(24, 32), 256, 0, stream>>>(Xbf, Wd, biasf, Qb, Kb, Vt);
  rope_kernel<<<8192, 256, 0, stream>>>(Qb, Kb);
  attn_kernel<<<dim3(32, 2, 16), 256, 0, stream>>>(Qb, Kb, Vt, OP, LP);
  combine_kernel<<<2048, 256, 0, stream>>>(OP, LP, Ab);
  gemm_o_kernel<<<dim3(8, 64), 256, 0, stream>>>(Ab, Wd + 3*1048576, biasf + 3072,
                                                 d_out, flag);
}

// Round 6
// 254.345 us; speedup vs baseline: 1.5563x; 1.0301x over previous
//
#include <hip/hip_runtime.h>
#include <stdint.h>

typedef unsigned short u16;
typedef unsigned int   u32;

#define NB   2
#define NS   2048
#define NDIM 1024
#define NH   16
#define NDH  64
// SCALE * log2(e) = 0.125 * 1.4426950408889634
#define QSCALE 0.18033688011112042f

typedef __bf16 bf16x8 __attribute__((ext_vector_type(8)));
typedef float  f32x4  __attribute__((ext_vector_type(4)));

#define MFMA_BF16(a,b,c) __builtin_amdgcn_mfma_f32_16x16x32_bf16((a),(b),(c),0,0,0)

// ---------------- ws layout (bytes) ----------------
#define XBF_OFF   (256)                          // 8 MB x bf16; reused as combined attention output
#define WD_OFF    (XBF_OFF  + 8*1024*1024)       // 8 MB dense quaternion weights (q,k,v,o)
#define BIAS_OFF  (WD_OFF   + 8*1024*1024)       // 16 KB fp32 biases
#define QB_OFF    (BIAS_OFF + 16384)             // 8 MB Q (bh,s,d) bf16 (roped, pre-scaled)
#define KB_OFF    (QB_OFF   + 8*1024*1024)       // 8 MB K (bh,s,d) (roped)
#define VT_OFF    (KB_OFF   + 8*1024*1024)       // 8 MB V^T (bh,d,s)
#define OP_OFF    (VT_OFF   + 8*1024*1024)       // 16 MB O partials bf16 [split][bh][s][d]
#define LP_OFF    (OP_OFF   + 16*1024*1024)      // 512 KB l partials fp32 [split][bh][s]

__device__ __forceinline__ float bf2f(u16 h){
  union { u32 u; float f; } v; v.u = ((u32)h) << 16; return v.f;
}
__device__ __forceinline__ u16 f2bf(float f){
  union { float f; u32 u; } v; v.f = f;
  u32 r = (v.u >> 16) & 1u;
  return (u16)((v.u + 0x7fffu + r) >> 16);
}
__device__ __forceinline__ float load_val(const void* p, int i, int isbf){
  return isbf ? bf2f(((const u16*)p)[i]) : ((const float*)p)[i];
}
__device__ __forceinline__ void gl_lds16(const u16* g, u16* l){
  __builtin_amdgcn_global_load_lds(
      (__attribute__((address_space(1))) void*)(uintptr_t)g,
      (__attribute__((address_space(3))) void*)(uintptr_t)l,
      16, 0, 0);
}

// ---------------- dtype detector ----------------
__global__ void detect_kernel(const u16* __restrict__ x, int* __restrict__ flag){
  __shared__ int cnt;
  if (threadIdx.x == 0) cnt = 0;
  __syncthreads();
  int ok = 0;
  int base = threadIdx.x * 16;
  for (int i = base; i < base + 16; ++i){
    u16 h = x[i];
    int e = (h >> 7) & 0xFF;
    if ((e > 96 && e < 158) || ((h & 0x7FFF) == 0)) ok++;
  }
  atomicAdd(&cnt, ok);
  __syncthreads();
  if (threadIdx.x == 0) *flag = (cnt > 3600) ? 1 : 0;
}

// ---------------- x -> bf16 ----------------
__global__ void conv_x_kernel(const void* __restrict__ xin, u16* __restrict__ xbf,
                              const int* __restrict__ flag){
  int isbf = *flag;
  int t = blockIdx.x * 256 + threadIdx.x;
  if (isbf){
    ((uint4*)xbf)[t] = ((const uint4*)xin)[t];
  } else {
    const float4* f4 = (const float4*)xin;
    float4 a = f4[2*t], b = f4[2*t+1];
    ushort4 lo = { f2bf(a.x), f2bf(a.y), f2bf(a.z), f2bf(a.w) };
    ushort4 hi = { f2bf(b.x), f2bf(b.y), f2bf(b.z), f2bf(b.w) };
    ((ushort4*)xbf)[2*t]   = lo;
    ((ushort4*)xbf)[2*t+1] = hi;
  }
}

// ---------------- dense quaternion weight build ----------------
struct QPtrs { const void* w[16]; const void* b[4]; };

__global__ void build_w_kernel(QPtrs ptrs, u16* __restrict__ wd,
                               float* __restrict__ biasf, const int* __restrict__ flag){
  int isbf = *flag;
  int idx = blockIdx.x * 256 + threadIdx.x;
  int n = idx & 255, m = (idx >> 8) & 255, c = (idx >> 16) & 3, p = idx >> 18;
  int src = m * 256 + n;
  float vr = load_val(ptrs.w[p*4+0], src, isbf);
  float vi = load_val(ptrs.w[p*4+1], src, isbf);
  float vj = load_val(ptrs.w[p*4+2], src, isbf);
  float vk = load_val(ptrs.w[p*4+3], src, isbf);
  float o0, o1, o2, o3;
  switch (c){
    case 0:  o0 = vr; o1 = -vi; o2 = -vj; o3 = -vk; break;
    case 1:  o0 = vi; o1 =  vr; o2 = -vj; o3 =  vk; break;
    case 2:  o0 = vj; o1 =  vi; o2 =  vr; o3 = -vk; break;
    default: o0 = vk; o1 = -vi; o2 =  vj; o3 =  vr; break;
  }
  ushort4 sv = { f2bf(o0), f2bf(o1), f2bf(o2), f2bf(o3) };
  *(ushort4*)&wd[(size_t)p * 1048576 + (size_t)(4*m + c) * 1024 + 4*n] = sv;
  if (idx < 4096){
    int pp = idx >> 10, oo = idx & 1023;
    biasf[idx] = load_val(ptrs.b[pp], oo, isbf);
  }
}

// ---------------- GEMM: X*Wqkv^T, fused bias+RoPE epilogue ----------------
// XOR chunk swizzle (global side) kills the 8-way fragment bank conflicts;
// double-buffered LDS gives prefetch a full MFMA-phase head start.
// K-loop: 32 iterations x BK=32 = K=1024 (round-5 bug: was 16).
__global__ __launch_bounds__(256)
void gemm_qkv_kernel(const u16* __restrict__ A, const u16* __restrict__ Bw,
                     const float* __restrict__ bias,
                     u16* __restrict__ qb, u16* __restrict__ kb, u16* __restrict__ vt){
  __shared__ u16 sA[2][128 * 32];
  __shared__ u16 sB[2][128 * 32];
  int tid = threadIdx.x, w = tid >> 6, lane = tid & 63, quad = lane >> 4, l16 = lane & 15;
  int n0 = blockIdx.x * 128, m0 = blockIdx.y * 128;

  f32x4 acc[4][4];
#pragma unroll
  for (int i = 0; i < 4; ++i)
#pragma unroll
    for (int j = 0; j < 4; ++j) acc[i][j] = (f32x4){0.f, 0.f, 0.f, 0.f};

  // staging: lane -> (row rl, chunk pos cp); fetch global chunk cp ^ ((rl>>1)&3)
  int cp = lane & 3, rl = lane >> 2;
  int gc = (cp ^ ((rl >> 1) & 3)) * 8;
  const u16* ga = A  + (size_t)(m0 + w*16 + rl) * 1024 + gc;
  const u16* gb = Bw + (size_t)(n0 + w*16 + rl) * 1024 + gc;
  int ldo = w * 512 + lane * 8;
  int xorv = ((l16 >> 1) & 3) * 8;
  int mw = (w & 1) * 64, nw = (w >> 1) * 64;

  auto stage = [&](int k0, int b){
#pragma unroll
    for (int i = 0; i < 2; ++i){
      gl_lds16(ga + (size_t)i * 65536 + k0, &sA[b][ldo + i * 2048]);
      gl_lds16(gb + (size_t)i * 65536 + k0, &sB[b][ldo + i * 2048]);
    }
  };

  stage(0, 0);
  for (int it = 0; it < 32; ++it){
    __syncthreads();
    if (it < 31) stage((it + 1) * 32, (it + 1) & 1);
    const u16* cA = sA[it & 1];
    const u16* cB = sB[it & 1];
    bf16x8 af[4], bfr[4];
#pragma unroll
    for (int mt = 0; mt < 4; ++mt)
      af[mt] = *(const bf16x8*)&cA[(mw + mt*16 + l16) * 32 + (quad*8 ^ xorv)];
#pragma unroll
    for (int nt = 0; nt < 4; ++nt)
      bfr[nt] = *(const bf16x8*)&cB[(nw + nt*16 + l16) * 32 + (quad*8 ^ xorv)];
#pragma unroll
    for (int mt = 0; mt < 4; ++mt)
#pragma unroll
      for (int nt = 0; nt < 4; ++nt)
        acc[mt][nt] = MFMA_BF16(af[mt], bfr[nt], acc[mt][nt]);
  }

  int proj = n0 >> 10;    // uniform per block (proj boundary is a multiple of 128)
  if (proj == 2){
    // V^T: [bh][d][s]
#pragma unroll
    for (int mt = 0; mt < 4; ++mt){
      int row = m0 + mw + mt*16 + quad*4;
      int b = row >> 11, seq0 = row & 2047;
#pragma unroll
      for (int nt = 0; nt < 4; ++nt){
        int col = n0 + nw + nt*16 + l16;
        int o = col & 1023, h = o >> 6, d = o & 63;
        float bv = bias[col];
        ushort4 pv = { f2bf(acc[mt][nt][0] + bv), f2bf(acc[mt][nt][1] + bv),
                       f2bf(acc[mt][nt][2] + bv), f2bf(acc[mt][nt][3] + bv) };
        *(ushort4*)&vt[((size_t)((b*16 + h) * 64 + d)) * 2048 + seq0] = pv;
      }
    }
  } else {
    // Q/K with fused RoPE: out = co*v + sgn*si*partner  (partner = lane xor (ax+1))
    float sc = (proj == 0) ? QSCALE : 1.0f;
    u16* dst = proj ? kb : qb;
    int c = l16 & 3;
#pragma unroll
    for (int nt = 0; nt < 4; ++nt){
      int col = n0 + nw + nt*16 + l16;
      int o = col & 1023, h = o >> 6, d = o & 63;
      int g = d >> 2;
      int ax = g % 3;
      int mask = ax + 1;
      int tbl = (ax == 0) ? 0xA : (ax == 1 ? 0x6 : 0xC);   // '+' bits by component
      float sgn = ((tbl >> c) & 1) ? 1.f : -1.f;
      float inv = __builtin_amdgcn_exp2f(-(float)g * 0.8304820237218405f); // 10000^(-g/16)
      float bv = bias[col];
#pragma unroll
      for (int mt = 0; mt < 4; ++mt){
        int row0 = m0 + mw + mt*16 + quad*4;
        int b = row0 >> 11, s0 = row0 & 2047;
        size_t obase = ((size_t)((b*16 + h) * 2048 + s0)) * 64 + d;
#pragma unroll
        for (int r = 0; r < 4; ++r){
          float v = acc[mt][nt][r] + bv;
          float vp = __shfl_xor(v, mask);
          float ang = (float)(s0 + r) * inv;
          float co = __cosf(ang) * sc;
          float si = __sinf(ang) * sc * sgn;
          dst[obase + (size_t)r * 64] = f2bf(co * v + si * vp);
        }
      }
    }
  }
}

// ---------------- GEMM: attn-out * Wo^T -> d_out (swizzled + dbuf) ----------------
__global__ __launch_bounds__(256)
void gemm_o_kernel(const u16* __restrict__ A, const u16* __restrict__ Bw,
                   const float* __restrict__ bias, void* __restrict__ dout,
                   const int* __restrict__ flag){
  __shared__ u16 sA[2][64 * 32];
  __shared__ u16 sB[2][128 * 32];
  int tid = threadIdx.x, w = tid >> 6, lane = tid & 63, quad = lane >> 4, l16 = lane & 15;
  int n0 = blockIdx.x * 128, m0 = blockIdx.y * 64;

  f32x4 acc[2][4];
#pragma unroll
  for (int i = 0; i < 2; ++i)
#pragma unroll
    for (int j = 0; j < 4; ++j) acc[i][j] = (f32x4){0.f, 0.f, 0.f, 0.f};

  int cp = lane & 3, rl = lane >> 2;
  int gc = (cp ^ ((rl >> 1) & 3)) * 8;
  int xorv = ((l16 >> 1) & 3) * 8;
  int mw = (w & 1) * 32, nw = (w >> 1) * 64;

  auto stage = [&](int k0, int b){
#pragma unroll
    for (int i = 0; i < 3; ++i){
      int ch = w * 3 + i;                 // 12 chunks: 4 sA + 8 sB
      int lr = (ch < 4 ? ch : ch - 4) * 16 + rl;
      int eo = (ch < 4 ? ch : ch - 4) * 512 + lane * 8;
      if (ch < 4) gl_lds16(A  + (size_t)(m0 + lr) * 1024 + k0 + gc, &sA[b][eo]);
      else        gl_lds16(Bw + (size_t)(n0 + lr) * 1024 + k0 + gc, &sB[b][eo]);
    }
  };

  stage(0, 0);
  for (int it = 0; it < 32; ++it){
    __syncthreads();
    if (it < 31) stage((it + 1) * 32, (it + 1) & 1);
    const u16* cA = sA[it & 1];
    const u16* cB = sB[it & 1];
    bf16x8 af[2], bfr[4];
#pragma unroll
    for (int mt = 0; mt < 2; ++mt)
      af[mt] = *(const bf16x8*)&cA[(mw + mt*16 + l16) * 32 + (quad*8 ^ xorv)];
#pragma unroll
    for (int nt = 0; nt < 4; ++nt)
      bfr[nt] = *(const bf16x8*)&cB[(nw + nt*16 + l16) * 32 + (quad*8 ^ xorv)];
#pragma unroll
    for (int mt = 0; mt < 2; ++mt)
#pragma unroll
      for (int nt = 0; nt < 4; ++nt)
        acc[mt][nt] = MFMA_BF16(af[mt], bfr[nt], acc[mt][nt]);
  }

  int isbf = *flag;
#pragma unroll
  for (int mt = 0; mt < 2; ++mt){
    int row = m0 + mw + mt*16 + quad*4;
#pragma unroll
    for (int nt = 0; nt < 4; ++nt){
      int col = n0 + nw + nt*16 + l16;
      float bv = bias[col];
#pragma unroll
      for (int r = 0; r < 4; ++r){
        float val = acc[mt][nt][r] + bv;
        size_t addr = (size_t)(row + r) * 1024 + col;
        if (isbf) ((u16*)dout)[addr] = f2bf(val);
        else      ((float*)dout)[addr] = val;
      }
    }
  }
}

// ---------------- flash attention v4 (unchanged, round-4 verified) ----------------
#define SPT 20

__global__ __launch_bounds__(256, 3)
void attn_kernel(const u16* __restrict__ Q, const u16* __restrict__ K,
                 const u16* __restrict__ Vt, u16* __restrict__ OP,
                 float* __restrict__ LP){
  __shared__ u16 sK[2][4096];
  __shared__ u16 sPT[4][64 * SPT];
  int bh  = blockIdx.x;
  int spl = blockIdx.y;
  int qt  = 15 - (int)blockIdx.z;
  int tid = threadIdx.x, w = tid >> 6, lane = tid & 63, quad = lane >> 4, l16 = lane & 15;
  size_t kbase = (size_t)bh * 2048 * 64;
  size_t vbase = (size_t)bh * 64 * 2048;
  int rowbase = qt * 128 + w * 32;
  u16* spw = &sPT[w][0];

  bf16x8 qf[2][2];
#pragma unroll
  for (int g = 0; g < 2; ++g)
#pragma unroll
    for (int kc = 0; kc < 2; ++kc)
      qf[g][kc] = *(const bf16x8*)(Q + kbase + (size_t)(rowbase + g*16 + l16) * 64 + kc*32 + quad*8);

  f32x4 oaccT[2][4];
  float lsum[2][4];
#pragma unroll
  for (int g = 0; g < 2; ++g)
#pragma unroll
    for (int i = 0; i < 4; ++i){ oaccT[g][i] = (f32x4){0.f,0.f,0.f,0.f}; lsum[g][i] = 0.f; }

  int kt0 = spl ? (qt + 1) : 0;
  int ntiles = qt + 1;

  auto stage = [&](int kt, int b){
    int kcol = kt * 64;
#pragma unroll
    for (int p = 0; p < 2; ++p){
      int slot = w*128 + p*64 + lane;
      int row = slot >> 3, dc = (slot & 7) ^ (row & 7);
      gl_lds16(K + kbase + (size_t)(kcol + row) * 64 + dc*8, &sK[b][(w*128 + p*64) * 8]);
    }
  };

  stage(kt0, 0);
  for (int i = 0; i < ntiles; ++i){
    int kcol = (kt0 + i) * 64;
    __syncthreads();
    if (i + 1 < ntiles) stage(kt0 + i + 1, (i + 1) & 1);
    const u16* bK = sK[i & 1];

    if (kcol <= rowbase + 31){
      bf16x8 vf[4][2];
#pragma unroll
      for (int dn = 0; dn < 4; ++dn)
#pragma unroll
        for (int kc = 0; kc < 2; ++kc)
          vf[dn][kc] = *(const bf16x8*)(Vt + vbase + (size_t)(dn*16 + l16) * 2048
                                        + kcol + kc*32 + quad*8);
      bf16x8 bk[2][4];
#pragma unroll
      for (int kc = 0; kc < 2; ++kc)
#pragma unroll
        for (int nt = 0; nt < 4; ++nt){
          int rw = nt*16 + l16;
          int ch = ((kc*4 + quad) ^ (rw & 7)) * 8;
          bk[kc][nt] = *(const bf16x8*)&bK[rw*64 + ch];
        }
#pragma unroll
      for (int g = 0; g < 2; ++g){
        int G0 = rowbase + g*16;
        if (kcol <= G0 + 15){
          f32x4 sacc[4];
#pragma unroll
          for (int nt = 0; nt < 4; ++nt) sacc[nt] = (f32x4){0.f,0.f,0.f,0.f};
#pragma unroll
          for (int kc = 0; kc < 2; ++kc)
#pragma unroll
            for (int nt = 0; nt < 4; ++nt)
              sacc[nt] = MFMA_BF16(qf[g][kc], bk[kc][nt], sacc[nt]);

          if (kcol + 63 > G0){
#pragma unroll
            for (int nt = 0; nt < 4; ++nt){
              int col = kcol + nt*16 + l16;
              ushort4 pv;
#pragma unroll
              for (int r = 0; r < 4; ++r){
                int row = G0 + quad*4 + r;
                float pp = (col <= row) ? __builtin_amdgcn_exp2f(sacc[nt][r]) : 0.f;
                lsum[g][r] += pp;
                ((u16*)&pv)[r] = f2bf(pp);
              }
              *(ushort4*)&spw[(nt*16 + l16) * SPT + quad*4] = pv;
            }
          } else {
#pragma unroll
            for (int nt = 0; nt < 4; ++nt){
              ushort4 pv;
#pragma unroll
              for (int r = 0; r < 4; ++r){
                float pp = __builtin_amdgcn_exp2f(sacc[nt][r]);
                lsum[g][r] += pp;
                ((u16*)&pv)[r] = f2bf(pp);
              }
              *(ushort4*)&spw[(nt*16 + l16) * SPT + quad*4] = pv;
            }
          }
#pragma unroll
          for (int kc = 0; kc < 2; ++kc){
            bf16x8 pf;
#pragma unroll
            for (int j = 0; j < 8; ++j)
              pf[j] = ((const __bf16*)spw)[(kc*32 + quad*8 + j) * SPT + l16];
#pragma unroll
            for (int dn = 0; dn < 4; ++dn)
              oaccT[g][dn] = MFMA_BF16(vf[dn][kc], pf, oaccT[g][dn]);
          }
        }
      }
    }
  }

  float* scr = (float*)spw;
#pragma unroll
  for (int g = 0; g < 2; ++g)
#pragma unroll
    for (int r = 0; r < 4; ++r){
      float l = lsum[g][r];
      l += __shfl_xor(l, 1); l += __shfl_xor(l, 2);
      l += __shfl_xor(l, 4); l += __shfl_xor(l, 8);
      if (l16 == 0) scr[g*16 + quad*4 + r] = l;
    }
  float lrow[2];
#pragma unroll
  for (int g = 0; g < 2; ++g) lrow[g] = scr[g*16 + l16];

  size_t obase = ((size_t)(spl*32 + bh)) * 2048;
#pragma unroll
  for (int g = 0; g < 2; ++g){
    int row = rowbase + g*16 + l16;
    if (quad == 0) LP[obase + row] = lrow[g];
#pragma unroll
    for (int dn = 0; dn < 4; ++dn){
      ushort4 ov = { f2bf(oaccT[g][dn][0]), f2bf(oaccT[g][dn][1]),
                     f2bf(oaccT[g][dn][2]), f2bf(oaccT[g][dn][3]) };
      *(ushort4*)&OP[(obase + row) * 64 + dn*16 + quad*4] = ov;
    }
  }
}

// ---------------- combine splits -> Ab (b, s, h*64+d) bf16 ----------------
__global__ void combine_kernel(const u16* __restrict__ OP, const float* __restrict__ LP,
                               u16* __restrict__ Ab){
  int idx = blockIdx.x * 256 + threadIdx.x;
  int dc = idx & 7, s = (idx >> 3) & 2047, bh = idx >> 14;
  size_t r0 = (size_t)bh * 2048 + s, r1 = (size_t)(32 + bh) * 2048 + s;
  float invl = 1.f / (LP[r0] + LP[r1]);
  union { uint4 v; u16 h[8]; } a0, a1; ushort4 o[2];
  a0.v = *(const uint4*)&OP[r0 * 64 + dc*8];
  a1.v = *(const uint4*)&OP[r1 * 64 + dc*8];
#pragma unroll
  for (int p = 0; p < 2; ++p)
#pragma unroll
    for (int j = 0; j < 4; ++j)
      ((u16*)&o[p])[j] = f2bf((bf2f(a0.h[p*4+j]) + bf2f(a1.h[p*4+j])) * invl);
  int b = bh >> 4, h = bh & 15;
  u16* dst = &Ab[((size_t)(b*2048 + s)) * 1024 + h*64 + dc*8];
  *(ushort4*)dst = o[0];
  *(ushort4*)(dst + 4) = o[1];
}

// ---------------- launcher ----------------
extern "C" void kernel_launch(void* const* d_in, const int* in_sizes, int n_in,
                              void* d_out, int out_size, void* d_ws, size_t ws_size,
                              hipStream_t stream){
  (void)in_sizes; (void)n_in; (void)out_size; (void)ws_size;
  char* ws = (char*)d_ws;
  int*   flag  = (int*)ws;
  u16*   Xbf   = (u16*)(ws + XBF_OFF);
  u16*   Wd    = (u16*)(ws + WD_OFF);
  float* biasf = (float*)(ws + BIAS_OFF);
  u16*   Qb    = (u16*)(ws + QB_OFF);
  u16*   Kb    = (u16*)(ws + KB_OFF);
  u16*   Vt    = (u16*)(ws + VT_OFF);
  u16*   OP    = (u16*)(ws + OP_OFF);
  float* LP    = (float*)(ws + LP_OFF);
  u16*   Ab    = Xbf;

  detect_kernel<<<1, 256, 0, stream>>>((const u16*)d_in[0], flag);
  conv_x_kernel<<<2048, 256, 0, stream>>>(d_in[0], Xbf, flag);

  QPtrs ptrs;
  for (int p = 0; p < 4; ++p){
    for (int wi = 0; wi < 4; ++wi) ptrs.w[p*4 + wi] = d_in[2 + p*5 + wi];
    ptrs.b[p] = d_in[2 + p*5 + 4];
  }
  build_w_kernel<<<4096, 256, 0, stream>>>(ptrs, Wd, biasf, flag);

  gemm_qkv_kernel<<<dim3(24, 32), 256, 0, stream>>>(Xbf, Wd, biasf, Qb, Kb, Vt);
  attn_kernel<<<dim3(32, 2, 16), 256, 0, stream>>>(Qb, Kb, Vt, OP, LP);
  combine_kernel<<<2048, 256, 0, stream>>>(OP, LP, Ab);
  gemm_o_kernel<<<dim3(8, 64), 256, 0, stream>>>(Ab, Wd + 3*1048576, biasf + 3072,
                                                 d_out, flag);
}